// Round 12
// baseline (803.495 us; speedup 1.0000x reference)
//
#include <hip/hip_runtime.h>
#include <hip/hip_bf16.h>
#include <stdint.h>

#define NF 256
#define EPSV 1e-5f
#define PB 160   // max bn partial blocks

typedef unsigned short u16;
typedef short short8 __attribute__((ext_vector_type(8)));
typedef float floatx4 __attribute__((ext_vector_type(4)));

// param block offsets (floats): 12 x 256, then 6 x 512, then 2 x 1
#define P_BGCN 0
#define P_G1 256
#define P_BE1 512
#define P_BAGG 768
#define P_AGG1 1024
#define P_AGBE1 1280
#define P_ASRC 1536
#define P_ADST 1792
#define P_BGAT 2048
#define P_ASRC2 2304
#define P_ADST2 2560
#define P_BGAT2 2816
#define P_G2 3072
#define P_BE2 3584
#define P_WFC 4096
#define P_AGG2 4608
#define P_AGBE2 5120
#define P_WAGFC 5632
#define P_BFC 6144
#define P_BAGFC 6145

__device__ __forceinline__ float bf2f(u16 u) {
    union { unsigned int i; float f; } v; v.i = ((unsigned int)u) << 16; return v.f;
}
__device__ __forceinline__ u16 f2bf(float f) {
    unsigned int x = __float_as_uint(f);
    unsigned int r = x + 0x7fffu + ((x >> 16) & 1u);
    return (u16)(r >> 16);
}
__device__ __forceinline__ float sane(float f) {
    return (f == f && fabsf(f) < 1e30f) ? f : 0.f;
}
__device__ __forceinline__ unsigned int zap2(unsigned int w) {
    if ((w & 0x00007F80u) == 0x00007F80u) w &= 0xFFFF0000u;
    if ((w & 0x7F800000u) == 0x7F800000u) w &= 0x0000FFFFu;
    return w;
}
__device__ __forceinline__ float lrelu(float x) { return x > 0.f ? x : 0.2f * x; }

__device__ __forceinline__ float4 ld4h(const u16* p) {
    uint2 u = *(const uint2*)p;
    float4 r;
    r.x = bf2f((u16)(u.x & 0xFFFFu)); r.y = bf2f((u16)(u.x >> 16));
    r.z = bf2f((u16)(u.y & 0xFFFFu)); r.w = bf2f((u16)(u.y >> 16));
    return r;
}
__device__ __forceinline__ void st4h(u16* p, float4 v) {
    uint2 u;
    u.x = (unsigned)f2bf(v.x) | ((unsigned)f2bf(v.y) << 16);
    u.y = (unsigned)f2bf(v.z) | ((unsigned)f2bf(v.w) << 16);
    *(uint2*)p = u;
}

__device__ __forceinline__ float wredsum(float v) {
#pragma unroll
    for (int o = 32; o > 0; o >>= 1) v += __shfl_xor(v, o, 64);
    return v;
}
__device__ __forceinline__ int wscan_incl(int x, int lane) {
#pragma unroll
    for (int o = 1; o < 64; o <<= 1) {
        int t = __shfl_up(x, o, 64);
        if (lane >= o) x += t;
    }
    return x;
}

// ---------------- dtype detect ----------------
__global__ void detect_k(const u16* __restrict__ x, int* __restrict__ flag) {
    __shared__ int cnt;
    if (threadIdx.x == 0) cnt = 0;
    __syncthreads();
    int c = 0;
#pragma unroll
    for (int k = 0; k < 4; ++k) {
        unsigned int u = x[2 * (threadIdx.x + 256 * k)];
        int e = (int)((u >> 7) & 0xFFu);
        if (u == 0u || (e >= 100 && e <= 140)) c++;
    }
    atomicAdd(&cnt, c);
    __syncthreads();
    if (threadIdx.x == 0) flag[0] = (cnt >= 512) ? 1 : 0;
}

// ---------------- prep: weight fragment-pack + param cvt + cnt3 zero ----------------
__global__ void prep_k(const void* w0, const void* w1, const void* w2, const void* w3,
                       const void* p0, const void* p1, const void* p2, const void* p3,
                       const void* p4, const void* p5, const void* p6, const void* p7,
                       const void* p8, const void* p9, const void* p10, const void* p11,
                       const void* p12, const void* p13, const void* p14, const void* p15,
                       const void* p16, const void* p17, const void* p18, const void* p19,
                       u16* __restrict__ wtf, float* __restrict__ prm,
                       int* __restrict__ cnt3, int ncnt,
                       const int* __restrict__ flagp) {
    int f = flagp[0];
    int idx = blockIdx.x * 256 + threadIdx.x;
    if (idx < ncnt) cnt3[idx] = 0;
    if (idx < 262144) {
        const void* ws[4] = {w0, w1, w2, w3};
        int wi = idx >> 16;
        int rest = idx & 65535;
        int j = rest & 7;
        int lr = (rest >> 3) & 15;
        int q = (rest >> 7) & 3;
        int nf = (rest >> 9) & 15;
        int ks = (rest >> 13) & 7;
        int n = nf * 16 + lr;
        int k = ks * 32 + q * 8 + j;
        const void* W = ws[wi];
        u16 v;
        if (f) {
            v = ((const u16*)W)[k * NF + n];
            if ((v & 0x7F80u) == 0x7F80u) v = 0;
        } else {
            v = f2bf(sane(((const float*)W)[k * NF + n]));
        }
        wtf[idx] = v;
        return;
    }
    int pidx = idx - 262144;
    if (pidx >= 6146) return;
    const void* ptrs[20] = {p0, p1, p2, p3, p4, p5, p6, p7, p8, p9,
                            p10, p11, p12, p13, p14, p15, p16, p17, p18, p19};
    int t, j;
    if (pidx < 3072) { t = pidx >> 8; j = pidx & 255; }
    else if (pidx < 6144) { t = 12 + ((pidx - 3072) >> 9); j = (pidx - 3072) & 511; }
    else { t = 18 + (pidx - 6144); j = 0; }
    float v = f ? bf2f(((const u16*)ptrs[t])[j]) : ((const float*)ptrs[t])[j];
    prm[pidx] = sane(v);
}

// ---------------- batched CSR build (y = graph: 0=ab, 1=ag, 2=d) ----------------
__global__ void cnt3_k(const int* e0, const int* e1, const int* e2,
                       int* __restrict__ cnt3, int NTp1) {
    int y = blockIdx.y;
    const int* ei = (y == 0) ? e0 : (y == 1) ? e1 : e2;
    int E = (y == 2) ? 640000 : 320000;
    int e = blockIdx.x * 256 + threadIdx.x;
    if (e < E) atomicAdd(&cnt3[y * NTp1 + ei[E + e]], 1);
}
__global__ __launch_bounds__(256) void scan_sum3_k(const int* __restrict__ cnt3,
                                                   int* __restrict__ bsum3, int NTp1) {
    __shared__ int wp[4];
    int y = blockIdx.y;
    int n = (y == 2) ? 40000 : 20000;
    int i = blockIdx.x * 256 + threadIdx.x;
    int lane = threadIdx.x & 63, wave = threadIdx.x >> 6;
    int v = (i < n) ? cnt3[y * NTp1 + i] : 0;
#pragma unroll
    for (int o = 32; o > 0; o >>= 1) v += __shfl_xor(v, o, 64);
    if (lane == 0) wp[wave] = v;
    __syncthreads();
    if (threadIdx.x == 0) bsum3[y * 256 + blockIdx.x] = wp[0] + wp[1] + wp[2] + wp[3];
}
__global__ __launch_bounds__(256) void scan_base3_k(int* __restrict__ bsum3,
                                                    int* rp0, int* rp1, int* rp2) {
    __shared__ int wp[4];
    int y = blockIdx.y;
    int n = (y == 2) ? 40000 : 20000;
    int nb = (n + 255) / 256;
    int* rp = (y == 0) ? rp0 : (y == 1) ? rp1 : rp2;
    int lane = threadIdx.x & 63, wave = threadIdx.x >> 6;
    int v = (threadIdx.x < nb) ? bsum3[y * 256 + threadIdx.x] : 0;
    int x = wscan_incl(v, lane);
    if (lane == 63) wp[wave] = x;
    __syncthreads();
    int off = 0;
#pragma unroll
    for (int w = 0; w < 4; ++w) off += (w < wave) ? wp[w] : 0;
    if (threadIdx.x < nb) bsum3[y * 256 + threadIdx.x] = off + x - v;
    if (threadIdx.x == 0) rp[n] = wp[0] + wp[1] + wp[2] + wp[3];
}
// also writes dinv for graphs 0,1 (dinv = rsqrt(indeg+1))
__global__ __launch_bounds__(256) void scan_fin3_k(const int* __restrict__ cnt3,
                                                   const int* __restrict__ bsum3,
                                                   int* rp0, int* rp1, int* rp2,
                                                   float* dv0, float* dv1, int NTp1) {
    __shared__ int wp[4];
    int y = blockIdx.y;
    int n = (y == 2) ? 40000 : 20000;
    int* rp = (y == 0) ? rp0 : (y == 1) ? rp1 : rp2;
    int i = blockIdx.x * 256 + threadIdx.x;
    int lane = threadIdx.x & 63, wave = threadIdx.x >> 6;
    int v = (i < n) ? cnt3[y * NTp1 + i] : 0;
    int x = wscan_incl(v, lane);
    if (lane == 63) wp[wave] = x;
    __syncthreads();
    int off = 0;
#pragma unroll
    for (int w = 0; w < 4; ++w) off += (w < wave) ? wp[w] : 0;
    if (i < n) {
        rp[i] = bsum3[y * 256 + blockIdx.x] + off + x - v;
        if (y == 0) dv0[i] = rsqrtf((float)(v + 1));
        else if (y == 1) dv1[i] = rsqrtf((float)(v + 1));
    }
}
// scatter using atomic decrement of the counts still stored in cnt3 (fills in reverse)
__global__ void scatter3_k(const int* e0, const int* e1, const int* e2,
                           const int* rp0, const int* rp1, const int* rp2,
                           int* __restrict__ cnt3,
                           int* c0, int* c1, int* c2, int NTp1) {
    int y = blockIdx.y;
    const int* ei = (y == 0) ? e0 : (y == 1) ? e1 : e2;
    const int* rp = (y == 0) ? rp0 : (y == 1) ? rp1 : rp2;
    int* col = (y == 0) ? c0 : (y == 1) ? c1 : c2;
    int E = (y == 2) ? 640000 : 320000;
    int e = blockIdx.x * 256 + threadIdx.x;
    if (e >= E) return;
    int s = ei[e], d = ei[E + e];
    int p = atomicAdd(&cnt3[y * NTp1 + d], -1) - 1;
    col[rp[d] + p] = s;
}

// ---------------- batched GCN GEMM (y = graph), LDS-free, MR=2, frag-ordered B ----------
__global__ __launch_bounds__(256) void gemm2_k(const void* A0, const void* A1,
                                               const u16* __restrict__ Wtf0,
                                               const u16* __restrict__ Wtf1,
                                               const int* __restrict__ flagp,
                                               u16* __restrict__ C, int M) {
    int f = flagp[0];
    int y = blockIdx.y;
    const void* Aptr = y ? A1 : A0;
    const u16* Wtf = y ? Wtf1 : Wtf0;
    u16* Cp = C + (size_t)y * M * NF;
    int wave = threadIdx.x >> 6, lane = threadIdx.x & 63;
    int lr = lane & 15, q = lane >> 4;
    int row0 = blockIdx.x * 128 + wave * 32;
    int ar0 = row0 + lr, ar1 = row0 + 16 + lr;
    bool ok0 = ar0 < M, ok1 = ar1 < M;
    floatx4 acc0[16], acc1[16];
#pragma unroll
    for (int nf = 0; nf < 16; ++nf) {
        acc0[nf] = (floatx4){0.f, 0.f, 0.f, 0.f};
        acc1[nf] = (floatx4){0.f, 0.f, 0.f, 0.f};
    }
    const u16* a16_0 = (const u16*)Aptr + (size_t)ar0 * NF;
    const u16* a16_1 = (const u16*)Aptr + (size_t)ar1 * NF;
    const float* a32_0 = (const float*)Aptr + (size_t)ar0 * NF;
    const float* a32_1 = (const float*)Aptr + (size_t)ar1 * NF;
#pragma unroll
    for (int ks = 0; ks < 8; ++ks) {
        int kk = ks * 32 + q * 8;
        union { u16 s[8]; uint4 u; short8 v; } a0, a1;
        if (f) {
            a0.u = ok0 ? *(const uint4*)(a16_0 + kk) : make_uint4(0u, 0u, 0u, 0u);
            a1.u = ok1 ? *(const uint4*)(a16_1 + kk) : make_uint4(0u, 0u, 0u, 0u);
            a0.u.x = zap2(a0.u.x); a0.u.y = zap2(a0.u.y);
            a0.u.z = zap2(a0.u.z); a0.u.w = zap2(a0.u.w);
            a1.u.x = zap2(a1.u.x); a1.u.y = zap2(a1.u.y);
            a1.u.z = zap2(a1.u.z); a1.u.w = zap2(a1.u.w);
        } else {
            if (ok0) {
                float4 f0 = *(const float4*)(a32_0 + kk);
                float4 f1 = *(const float4*)(a32_0 + kk + 4);
                a0.s[0] = f2bf(sane(f0.x)); a0.s[1] = f2bf(sane(f0.y));
                a0.s[2] = f2bf(sane(f0.z)); a0.s[3] = f2bf(sane(f0.w));
                a0.s[4] = f2bf(sane(f1.x)); a0.s[5] = f2bf(sane(f1.y));
                a0.s[6] = f2bf(sane(f1.z)); a0.s[7] = f2bf(sane(f1.w));
            } else a0.u = make_uint4(0u, 0u, 0u, 0u);
            if (ok1) {
                float4 f0 = *(const float4*)(a32_1 + kk);
                float4 f1 = *(const float4*)(a32_1 + kk + 4);
                a1.s[0] = f2bf(sane(f0.x)); a1.s[1] = f2bf(sane(f0.y));
                a1.s[2] = f2bf(sane(f0.z)); a1.s[3] = f2bf(sane(f0.w));
                a1.s[4] = f2bf(sane(f1.x)); a1.s[5] = f2bf(sane(f1.y));
                a1.s[6] = f2bf(sane(f1.z)); a1.s[7] = f2bf(sane(f1.w));
            } else a1.u = make_uint4(0u, 0u, 0u, 0u);
        }
        const u16* bbase = Wtf + ks * 8192 + lane * 8;
#pragma unroll
        for (int nf = 0; nf < 16; ++nf) {
            short8 b = *(const short8*)(bbase + nf * 512);
            acc0[nf] = __builtin_amdgcn_mfma_f32_16x16x32_bf16(a0.v, b, acc0[nf], 0, 0, 0);
            acc1[nf] = __builtin_amdgcn_mfma_f32_16x16x32_bf16(a1.v, b, acc1[nf], 0, 0, 0);
        }
    }
#pragma unroll
    for (int nf = 0; nf < 16; ++nf) {
#pragma unroll
        for (int rr = 0; rr < 4; ++rr) {
            int gr0 = row0 + q * 4 + rr;
            int gr1 = row0 + 16 + q * 4 + rr;
            if (gr0 < M) Cp[(size_t)gr0 * NF + nf * 16 + lr] = f2bf(acc0[nf][rr]);
            if (gr1 < M) Cp[(size_t)gr1 * NF + nf * 16 + lr] = f2bf(acc1[nf][rr]);
        }
    }
}

// ---------------- GAT GEMM, MR=2, fused scores epilogue (bf16 ws input) ----------------
__global__ __launch_bounds__(256) void gemm_gat_k(const u16* __restrict__ Aptr,
                                                  const u16* __restrict__ Wtf,
                                                  u16* __restrict__ C, int M,
                                                  const float* __restrict__ as_,
                                                  const float* __restrict__ ad_,
                                                  float* __restrict__ es,
                                                  float* __restrict__ ed) {
    int wave = threadIdx.x >> 6, lane = threadIdx.x & 63;
    int lr = lane & 15, q = lane >> 4;
    int row0 = blockIdx.x * 128 + wave * 32;
    int ar0 = row0 + lr, ar1 = row0 + 16 + lr;
    bool ok0 = ar0 < M, ok1 = ar1 < M;
    floatx4 acc0[16], acc1[16];
#pragma unroll
    for (int nf = 0; nf < 16; ++nf) {
        acc0[nf] = (floatx4){0.f, 0.f, 0.f, 0.f};
        acc1[nf] = (floatx4){0.f, 0.f, 0.f, 0.f};
    }
    const u16* a16_0 = Aptr + (size_t)ar0 * NF;
    const u16* a16_1 = Aptr + (size_t)ar1 * NF;
#pragma unroll
    for (int ks = 0; ks < 8; ++ks) {
        int kk = ks * 32 + q * 8;
        union { uint4 u; short8 v; } a0, a1;
        a0.u = ok0 ? *(const uint4*)(a16_0 + kk) : make_uint4(0u, 0u, 0u, 0u);
        a1.u = ok1 ? *(const uint4*)(a16_1 + kk) : make_uint4(0u, 0u, 0u, 0u);
        const u16* bbase = Wtf + ks * 8192 + lane * 8;
#pragma unroll
        for (int nf = 0; nf < 16; ++nf) {
            short8 b = *(const short8*)(bbase + nf * 512);
            acc0[nf] = __builtin_amdgcn_mfma_f32_16x16x32_bf16(a0.v, b, acc0[nf], 0, 0, 0);
            acc1[nf] = __builtin_amdgcn_mfma_f32_16x16x32_bf16(a1.v, b, acc1[nf], 0, 0, 0);
        }
    }
#pragma unroll
    for (int nf = 0; nf < 16; ++nf) {
#pragma unroll
        for (int rr = 0; rr < 4; ++rr) {
            int gr0 = row0 + q * 4 + rr;
            int gr1 = row0 + 16 + q * 4 + rr;
            if (gr0 < M) C[(size_t)gr0 * NF + nf * 16 + lr] = f2bf(acc0[nf][rr]);
            if (gr1 < M) C[(size_t)gr1 * NF + nf * 16 + lr] = f2bf(acc1[nf][rr]);
        }
    }
    // fused scores (fp32 acc): s[row] = sum_c h[row][c]*a[c]
    float asl[16], adl[16];
#pragma unroll
    for (int nf = 0; nf < 16; ++nf) { asl[nf] = as_[nf * 16 + lr]; adl[nf] = ad_[nf * 16 + lr]; }
#pragma unroll
    for (int rr = 0; rr < 4; ++rr) {
        float s10 = 0.f, s20 = 0.f, s11 = 0.f, s21 = 0.f;
#pragma unroll
        for (int nf = 0; nf < 16; ++nf) {
            s10 += acc0[nf][rr] * asl[nf];
            s20 += acc0[nf][rr] * adl[nf];
            s11 += acc1[nf][rr] * asl[nf];
            s21 += acc1[nf][rr] * adl[nf];
        }
#pragma unroll
        for (int o = 1; o < 16; o <<= 1) {
            s10 += __shfl_xor(s10, o, 64);
            s20 += __shfl_xor(s20, o, 64);
            s11 += __shfl_xor(s11, o, 64);
            s21 += __shfl_xor(s21, o, 64);
        }
        int gr0 = row0 + q * 4 + rr;
        int gr1 = row0 + 16 + q * 4 + rr;
        if (lr == 0) {
            if (gr0 < M) { es[gr0] = s10; ed[gr0] = s20; }
            if (gr1 < M) { es[gr1] = s11; ed[gr1] = s21; }
        }
    }
}

// ---------------- batched GCN aggregation via CSR (y = graph) ----------------
__global__ __launch_bounds__(256) void gcn_csr2_k(const u16* __restrict__ h,
                                                  const int* rp0, const int* rp1,
                                                  const int* c0, const int* c1,
                                                  const float* dv0, const float* dv1,
                                                  const float* __restrict__ prm,
                                                  u16* __restrict__ out, int n) {
    int y = blockIdx.y;
    const int* rp = y ? rp1 : rp0;
    const int* col = y ? c1 : c0;
    const float* dinv = y ? dv1 : dv0;
    const float* b = prm + (y ? P_BAGG : P_BGCN);
    const u16* hb = h + (size_t)y * n * NF;
    u16* ob = out + (size_t)y * n * NF;
    int wave = threadIdx.x >> 6, lane = threadIdx.x & 63;
    int i = blockIdx.x * 4 + wave;
    if (i >= n) return;
    int c = lane * 4;
    int beg = rp[i], end = rp[i + 1];
    float di = dinv[i];
    float4 hv = ld4h(hb + (size_t)i * NF + c);
    float w = di * di;
    float4 acc;
    acc.x = hv.x * w + b[c + 0];
    acc.y = hv.y * w + b[c + 1];
    acc.z = hv.z * w + b[c + 2];
    acc.w = hv.w * w + b[c + 3];
    int j = beg;
    for (; j + 3 < end; j += 4) {
        int s0 = col[j], s1 = col[j + 1], s2 = col[j + 2], s3 = col[j + 3];
        float n0 = dinv[s0] * di, n1 = dinv[s1] * di, n2 = dinv[s2] * di, n3 = dinv[s3] * di;
        float4 h0 = ld4h(hb + (size_t)s0 * NF + c);
        float4 h1 = ld4h(hb + (size_t)s1 * NF + c);
        float4 h2 = ld4h(hb + (size_t)s2 * NF + c);
        float4 h3 = ld4h(hb + (size_t)s3 * NF + c);
        acc.x += h0.x * n0 + h1.x * n1 + h2.x * n2 + h3.x * n3;
        acc.y += h0.y * n0 + h1.y * n1 + h2.y * n2 + h3.y * n3;
        acc.z += h0.z * n0 + h1.z * n1 + h2.z * n2 + h3.z * n3;
        acc.w += h0.w * n0 + h1.w * n1 + h2.w * n2 + h3.w * n3;
    }
    for (; j < end; ++j) {
        int s = col[j];
        float nrm = dinv[s] * di;
        float4 hs = ld4h(hb + (size_t)s * NF + c);
        acc.x += hs.x * nrm;
        acc.y += hs.y * nrm;
        acc.z += hs.z * nrm;
        acc.w += hs.w * nrm;
    }
    st4h(ob + (size_t)i * NF + c, acc);
}

// ---------------- BN partial stats (no atomics) ----------------
__global__ void bn_stats2_k(const u16* __restrict__ x, int n,
                            float* __restrict__ psum, float* __restrict__ psq) {
    int y = blockIdx.y;
    int c = threadIdx.x;  // 256
    int r0 = blockIdx.x * 128;
    int rend = min(r0 + 128, n);
    const u16* xb = x + (size_t)y * n * NF;
    float s = 0.f, qq = 0.f;
    for (int r = r0; r < rend; ++r) {
        float v = bf2f(xb[(size_t)r * NF + c]);
        s += v; qq += v * v;
    }
    size_t o = (size_t)(y * PB + blockIdx.x) * 512 + c;
    psum[o] = s; psq[o] = qq;
}
__global__ void bn_fin2_k(const float* __restrict__ psum, const float* __restrict__ psq,
                          float* __restrict__ stg, int n, int nb) {
    int y = blockIdx.y;
    int c = threadIdx.x;  // 256
    float s = 0.f, qq = 0.f;
    for (int b = 0; b < nb; ++b) {
        size_t o = (size_t)(y * PB + b) * 512 + c;
        s += psum[o]; qq += psq[o];
    }
    float inv_n = 1.0f / (float)n;
    float mean = s * inv_n;
    float var = fmaxf(qq * inv_n - mean * mean, 0.f);
    stg[y * 512 + c] = mean;
    stg[y * 512 + 256 + c] = rsqrtf(var + EPSV);
}
__global__ void bn_apply2_k(const u16* __restrict__ x, const float* __restrict__ stg,
                            const float* __restrict__ prm, u16* __restrict__ out, int n) {
    int y = blockIdx.y;
    int t = blockIdx.x * 256 + threadIdx.x;
    if (t >= n * NF) return;
    int c = t & 255;
    const float* st = stg + y * 512;
    const float* g = prm + (y ? P_AGG1 : P_G1);
    const float* be = prm + (y ? P_AGBE1 : P_BE1);
    float v = (bf2f(x[(size_t)y * n * NF + t]) - st[c]) * st[256 + c] * g[c] + be[c];
    out[(size_t)y * n * NF + t] = f2bf(fmaxf(v, 0.f));
}

// ---------------- single-pass fused GAT aggregation via CSR ----------------
// softmax without max-subtraction (scores are O(1): dots of O(1) activations with
// 1/sqrt(256)-scaled vectors; |e| << 88 so exp() cannot overflow). alpha = exp(e)/sum.
__global__ __launch_bounds__(256) void gat_csr_k(const u16* __restrict__ h,
                                                 const int* __restrict__ rp,
                                                 const int* __restrict__ col,
                                                 const float* __restrict__ es,
                                                 const float* __restrict__ ed,
                                                 const float* __restrict__ b,
                                                 u16* __restrict__ out, int n,
                                                 int do_relu) {
    int wave = threadIdx.x >> 6, lane = threadIdx.x & 63;
    int i = blockIdx.x * 4 + wave;
    if (i >= n) return;
    int beg = rp[i], end = rp[i + 1];
    float edi = ed[i];
    float ws = __expf(lrelu(es[i] + edi));
    int c = lane * 4;
    float4 hv = ld4h(h + (size_t)i * NF + c);
    float ssum = ws;
    float4 acc;
    acc.x = ws * hv.x; acc.y = ws * hv.y; acc.z = ws * hv.z; acc.w = ws * hv.w;
    int j = beg;
    for (; j + 3 < end; j += 4) {
        int s0 = col[j], s1 = col[j + 1], s2 = col[j + 2], s3 = col[j + 3];
        float4 h0 = ld4h(h + (size_t)s0 * NF + c);
        float4 h1 = ld4h(h + (size_t)s1 * NF + c);
        float4 h2 = ld4h(h + (size_t)s2 * NF + c);
        float4 h3 = ld4h(h + (size_t)s3 * NF + c);
        float a0 = __expf(lrelu(es[s0] + edi));
        float a1 = __expf(lrelu(es[s1] + edi));
        float a2 = __expf(lrelu(es[s2] + edi));
        float a3 = __expf(lrelu(es[s3] + edi));
        ssum += a0 + a1 + a2 + a3;
        acc.x += h0.x * a0 + h1.x * a1 + h2.x * a2 + h3.x * a3;
        acc.y += h0.y * a0 + h1.y * a1 + h2.y * a2 + h3.y * a3;
        acc.z += h0.z * a0 + h1.z * a1 + h2.z * a2 + h3.z * a3;
        acc.w += h0.w * a0 + h1.w * a1 + h2.w * a2 + h3.w * a3;
    }
    for (; j < end; ++j) {
        int s = col[j];
        float a = __expf(lrelu(es[s] + edi));
        float4 hs = ld4h(h + (size_t)s * NF + c);
        ssum += a;
        acc.x += a * hs.x;
        acc.y += a * hs.y;
        acc.z += a * hs.z;
        acc.w += a * hs.w;
    }
    float inv = 1.0f / ssum;
    acc.x = b[c + 0] + acc.x * inv;
    acc.y = b[c + 1] + acc.y * inv;
    acc.z = b[c + 2] + acc.z * inv;
    acc.w = b[c + 3] + acc.w * inv;
    if (do_relu) {
        acc.x = fmaxf(acc.x, 0.f); acc.y = fmaxf(acc.y, 0.f);
        acc.z = fmaxf(acc.z, 0.f); acc.w = fmaxf(acc.w, 0.f);
    }
    st4h(out + (size_t)i * NF + c, acc);
}

// ---------------- batched final-stage BN stats over cat(x,h) (512 ch) ----------------
__global__ void bn_stats_cat2_k(const u16* __restrict__ xp, const u16* __restrict__ hp,
                                int n, float* __restrict__ psum, float* __restrict__ psq) {
    int y = blockIdx.y;
    int c = threadIdx.x;  // 512
    int r0 = blockIdx.x * 128;
    int rend = min(r0 + 128, n);
    const u16* src = ((c < 256) ? xp : hp) + (size_t)y * n * NF;
    int cc = c & 255;
    float s = 0.f, qq = 0.f;
    for (int r = r0; r < rend; ++r) {
        float v = bf2f(src[(size_t)r * NF + cc]);
        s += v; qq += v * v;
    }
    size_t o = (size_t)(y * PB + blockIdx.x) * 512 + c;
    psum[o] = s; psq[o] = qq;
}
__global__ void bn_fin_cat2_k(const float* __restrict__ psum, const float* __restrict__ psq,
                              float* __restrict__ stc, int n, int nb) {
    int y = blockIdx.y;
    int c = threadIdx.x;  // 512
    float s = 0.f, qq = 0.f;
    for (int b = 0; b < nb; ++b) {
        size_t o = (size_t)(y * PB + b) * 512 + c;
        s += psum[o]; qq += psq[o];
    }
    float inv_n = 1.0f / (float)n;
    float mean = s * inv_n;
    float var = fmaxf(qq * inv_n - mean * mean, 0.f);
    stc[y * 1024 + c] = mean;
    stc[y * 1024 + 512 + c] = rsqrtf(var + EPSV);
}
__global__ void final2_k(const u16* __restrict__ xp, const u16* __restrict__ hp,
                         const float* __restrict__ stc, const float* __restrict__ prm,
                         float* __restrict__ out, int n) {
    int y = blockIdx.y;
    int wave = threadIdx.x >> 6, lane = threadIdx.x & 63;
    int i = blockIdx.x * 4 + wave;
    if (i >= n) return;
    const float* st = stc + y * 1024;
    const float* g = prm + (y ? P_AGG2 : P_G2);
    const float* be = prm + (y ? P_AGBE2 : P_BE2);
    const float* w = prm + (y ? P_WAGFC : P_WFC);
    float bias = prm[y ? P_BAGFC : P_BFC];
    const u16* src = (((lane < 32) ? xp : hp) + (size_t)y * n * NF) + (size_t)i * NF
                     + (lane < 32 ? lane * 8 : (lane - 32) * 8);
    uint4 u = *(const uint4*)src;
    float vv[8];
    vv[0] = bf2f((u16)(u.x & 0xFFFFu)); vv[1] = bf2f((u16)(u.x >> 16));
    vv[2] = bf2f((u16)(u.y & 0xFFFFu)); vv[3] = bf2f((u16)(u.y >> 16));
    vv[4] = bf2f((u16)(u.z & 0xFFFFu)); vv[5] = bf2f((u16)(u.z >> 16));
    vv[6] = bf2f((u16)(u.w & 0xFFFFu)); vv[7] = bf2f((u16)(u.w >> 16));
    int c0 = lane * 8;
    float acc = 0.f;
#pragma unroll
    for (int j = 0; j < 8; ++j) {
        int c = c0 + j;
        float v = (vv[j] - st[c]) * st[512 + c] * g[c] + be[c];
        v = fmaxf(v, 0.f);
        acc += v * w[c];
    }
    acc = wredsum(acc);
    if (lane == 0) out[(size_t)y * 20000 + i] = acc + bias;
}

// ---------------- host ----------------
extern "C" void kernel_launch(void* const* d_in, const int* in_sizes, int n_in,
                              void* d_out, int out_size, void* d_ws, size_t ws_size,
                              hipStream_t stream) {
    const void* x_ab = d_in[0];
    const void* x_ag = d_in[1];
    const int* e_ab = (const int*)d_in[26];
    const int* e_ag = (const int*)d_in[27];
    const int* e_d = (const int*)d_in[28];

    const int NAB = 20000, NT = 40000;
    const int EAB = 320000, EAG = 320000, ED = 640000;
    const int NTp1 = NT + 1;

    u16* hcat = (u16*)d_ws;                     // NT*NF u16
    u16* bufA = hcat + (size_t)NT * NF;         // NT*NF u16
    u16* bufB = bufA + (size_t)NT * NF;         // NT*NF u16
    u16* wt4 = bufB + (size_t)NT * NF;          // 4*65536 u16
    float* dv0 = (float*)(wt4 + 4 * 65536);     // NAB
    float* dv1 = dv0 + NAB;                     // NAB
    float* es = dv1 + NAB;                      // NT
    float* edv = es + NT;                       // NT
    float* stg = edv + NT;                      // 1024
    float* stc = stg + 1024;                    // 2048
    float* psum = stc + 2048;                   // 2*PB*512
    float* psq = psum + 2 * PB * 512;           // 2*PB*512
    float* prm = psq + 2 * PB * 512;            // 8192
    int* flag = (int*)(prm + 8192);             // 16
    int* rp_ab = flag + 16;                     // NAB+1
    int* rp_ag = rp_ab + NAB + 1;               // NAB+1
    int* rp_d = rp_ag + NAB + 1;                // NT+1
    int* cnt3 = rp_d + NT + 1;                  // 3*(NT+1)
    int* bsum3 = cnt3 + 3 * NTp1;               // 768
    int* col_ab = bsum3 + 768;                  // EAB
    int* col_ag = col_ab + EAB;                 // EAG
    int* col_d = col_ag + EAG;                  // ED

    u16* wt_gcn = wt4;
    u16* wt_aggcn = wt4 + 65536;
    u16* wt_gat = wt4 + 2 * 65536;
    u16* wt_gat2 = wt4 + 3 * 65536;

    dim3 t256(256), t512(512);
    const int nbg = (NAB + 127) / 128;   // 157 bn partial blocks per graph

    detect_k<<<dim3(1), t256, 0, stream>>>((const u16*)x_ab, flag);
    prep_k<<<dim3(1049), t256, 0, stream>>>(
        d_in[2], d_in[6], d_in[10], d_in[14],
        d_in[3], d_in[4], d_in[5], d_in[7], d_in[8], d_in[9],
        d_in[11], d_in[12], d_in[13], d_in[15], d_in[16], d_in[17],
        d_in[22], d_in[23], d_in[24], d_in[18], d_in[19], d_in[20],
        d_in[25], d_in[21], wt4, prm, cnt3, 3 * NTp1, flag);

    // batched CSR build (5 dispatches)
    cnt3_k<<<dim3(2500, 3), t256, 0, stream>>>(e_ab, e_ag, e_d, cnt3, NTp1);
    scan_sum3_k<<<dim3(157, 3), t256, 0, stream>>>(cnt3, bsum3, NTp1);
    scan_base3_k<<<dim3(1, 3), t256, 0, stream>>>(bsum3, rp_ab, rp_ag, rp_d);
    scan_fin3_k<<<dim3(157, 3), t256, 0, stream>>>(cnt3, bsum3, rp_ab, rp_ag, rp_d,
                                                   dv0, dv1, NTp1);
    scatter3_k<<<dim3(2500, 3), t256, 0, stream>>>(e_ab, e_ag, e_d, rp_ab, rp_ag, rp_d,
                                                   cnt3, col_ab, col_ag, col_d, NTp1);

    // batched GCN stage (5 dispatches)
    gemm2_k<<<dim3((NAB + 127) / 128, 2), t256, 0, stream>>>(x_ab, x_ag, wt_gcn, wt_aggcn,
                                                             flag, bufA, NAB);
    gcn_csr2_k<<<dim3((NAB + 3) / 4, 2), t256, 0, stream>>>(bufA, rp_ab, rp_ag,
                                                            col_ab, col_ag, dv0, dv1,
                                                            prm, bufB, NAB);
    bn_stats2_k<<<dim3(nbg, 2), t256, 0, stream>>>(bufB, NAB, psum, psq);
    bn_fin2_k<<<dim3(1, 2), t256, 0, stream>>>(psum, psq, stg, NAB, nbg);
    bn_apply2_k<<<dim3((NAB * NF + 255) / 256, 2), t256, 0, stream>>>(bufB, stg, prm,
                                                                      hcat, NAB);

    // GAT layer 1 (2 dispatches)
    gemm_gat_k<<<dim3((NT + 127) / 128), t256, 0, stream>>>(hcat, wt_gat, bufA, NT,
                                                            prm + P_ASRC, prm + P_ADST,
                                                            es, edv);
    gat_csr_k<<<dim3((NT + 3) / 4), t256, 0, stream>>>(bufA, rp_d, col_d, es, edv,
                                                       prm + P_BGAT, bufB, NT, 1);
    // GAT layer 2 (2 dispatches)
    gemm_gat_k<<<dim3((NT + 127) / 128), t256, 0, stream>>>(bufB, wt_gat2, bufA, NT,
                                                            prm + P_ASRC2, prm + P_ADST2,
                                                            es, edv);
    gat_csr_k<<<dim3((NT + 3) / 4), t256, 0, stream>>>(bufA, rp_d, col_d, es, edv,
                                                       prm + P_BGAT2, bufB, NT, 0);

    // batched final stage (3 dispatches)
    bn_stats_cat2_k<<<dim3(nbg, 2), t512, 0, stream>>>(bufB, hcat, NAB, psum, psq);
    bn_fin_cat2_k<<<dim3(1, 2), t512, 0, stream>>>(psum, psq, stc, NAB, nbg);
    final2_k<<<dim3((NAB + 3) / 4, 2), t256, 0, stream>>>(bufB, hcat, stc, prm,
                                                          (float*)d_out, NAB);
}

// Round 13
// 711.834 us; speedup vs baseline: 1.1288x; 1.1288x over previous
//
#include <hip/hip_runtime.h>
#include <hip/hip_bf16.h>
#include <stdint.h>

#define NF 256
#define EPSV 1e-5f
#define PB 160   // max bn partial blocks

typedef unsigned short u16;
typedef short short8 __attribute__((ext_vector_type(8)));
typedef float floatx4 __attribute__((ext_vector_type(4)));

// param block offsets (floats): 12 x 256, then 6 x 512, then 2 x 1
#define P_BGCN 0
#define P_G1 256
#define P_BE1 512
#define P_BAGG 768
#define P_AGG1 1024
#define P_AGBE1 1280
#define P_ASRC 1536
#define P_ADST 1792
#define P_BGAT 2048
#define P_ASRC2 2304
#define P_ADST2 2560
#define P_BGAT2 2816
#define P_G2 3072
#define P_BE2 3584
#define P_WFC 4096
#define P_AGG2 4608
#define P_AGBE2 5120
#define P_WAGFC 5632
#define P_BFC 6144
#define P_BAGFC 6145

__device__ __forceinline__ float bf2f(u16 u) {
    union { unsigned int i; float f; } v; v.i = ((unsigned int)u) << 16; return v.f;
}
__device__ __forceinline__ u16 f2bf(float f) {
    unsigned int x = __float_as_uint(f);
    unsigned int r = x + 0x7fffu + ((x >> 16) & 1u);
    return (u16)(r >> 16);
}
__device__ __forceinline__ float sane(float f) {
    return (f == f && fabsf(f) < 1e30f) ? f : 0.f;
}
__device__ __forceinline__ unsigned int zap2(unsigned int w) {
    if ((w & 0x00007F80u) == 0x00007F80u) w &= 0xFFFF0000u;
    if ((w & 0x7F800000u) == 0x7F800000u) w &= 0x0000FFFFu;
    return w;
}
__device__ __forceinline__ float lrelu(float x) { return x > 0.f ? x : 0.2f * x; }

__device__ __forceinline__ float4 ld4h(const u16* p) {
    uint2 u = *(const uint2*)p;
    float4 r;
    r.x = bf2f((u16)(u.x & 0xFFFFu)); r.y = bf2f((u16)(u.x >> 16));
    r.z = bf2f((u16)(u.y & 0xFFFFu)); r.w = bf2f((u16)(u.y >> 16));
    return r;
}
__device__ __forceinline__ void st4h(u16* p, float4 v) {
    uint2 u;
    u.x = (unsigned)f2bf(v.x) | ((unsigned)f2bf(v.y) << 16);
    u.y = (unsigned)f2bf(v.z) | ((unsigned)f2bf(v.w) << 16);
    *(uint2*)p = u;
}

__device__ __forceinline__ float wredsum(float v) {
#pragma unroll
    for (int o = 32; o > 0; o >>= 1) v += __shfl_xor(v, o, 64);
    return v;
}
__device__ __forceinline__ int wscan_incl(int x, int lane) {
#pragma unroll
    for (int o = 1; o < 64; o <<= 1) {
        int t = __shfl_up(x, o, 64);
        if (lane >= o) x += t;
    }
    return x;
}

// ---------------- dtype detect ----------------
__global__ void detect_k(const u16* __restrict__ x, int* __restrict__ flag) {
    __shared__ int cnt;
    if (threadIdx.x == 0) cnt = 0;
    __syncthreads();
    int c = 0;
#pragma unroll
    for (int k = 0; k < 4; ++k) {
        unsigned int u = x[2 * (threadIdx.x + 256 * k)];
        int e = (int)((u >> 7) & 0xFFu);
        if (u == 0u || (e >= 100 && e <= 140)) c++;
    }
    atomicAdd(&cnt, c);
    __syncthreads();
    if (threadIdx.x == 0) flag[0] = (cnt >= 512) ? 1 : 0;
}

// ---------------- prep: weight fragment-pack + param cvt + cnt3 zero ----------------
__global__ void prep_k(const void* w0, const void* w1, const void* w2, const void* w3,
                       const void* p0, const void* p1, const void* p2, const void* p3,
                       const void* p4, const void* p5, const void* p6, const void* p7,
                       const void* p8, const void* p9, const void* p10, const void* p11,
                       const void* p12, const void* p13, const void* p14, const void* p15,
                       const void* p16, const void* p17, const void* p18, const void* p19,
                       u16* __restrict__ wtf, float* __restrict__ prm,
                       int* __restrict__ cnt3, int ncnt,
                       const int* __restrict__ flagp) {
    int f = flagp[0];
    int idx = blockIdx.x * 256 + threadIdx.x;
    if (idx < ncnt) cnt3[idx] = 0;
    if (idx < 262144) {
        const void* ws[4] = {w0, w1, w2, w3};
        int wi = idx >> 16;
        int rest = idx & 65535;
        int j = rest & 7;
        int lr = (rest >> 3) & 15;
        int q = (rest >> 7) & 3;
        int nf = (rest >> 9) & 15;
        int ks = (rest >> 13) & 7;
        int n = nf * 16 + lr;
        int k = ks * 32 + q * 8 + j;
        const void* W = ws[wi];
        u16 v;
        if (f) {
            v = ((const u16*)W)[k * NF + n];
            if ((v & 0x7F80u) == 0x7F80u) v = 0;
        } else {
            v = f2bf(sane(((const float*)W)[k * NF + n]));
        }
        wtf[idx] = v;
        return;
    }
    int pidx = idx - 262144;
    if (pidx >= 6146) return;
    const void* ptrs[20] = {p0, p1, p2, p3, p4, p5, p6, p7, p8, p9,
                            p10, p11, p12, p13, p14, p15, p16, p17, p18, p19};
    int t, j;
    if (pidx < 3072) { t = pidx >> 8; j = pidx & 255; }
    else if (pidx < 6144) { t = 12 + ((pidx - 3072) >> 9); j = (pidx - 3072) & 511; }
    else { t = 18 + (pidx - 6144); j = 0; }
    float v = f ? bf2f(((const u16*)ptrs[t])[j]) : ((const float*)ptrs[t])[j];
    prm[pidx] = sane(v);
}

// ---------------- batched CSR build (y = graph: 0=ab, 1=ag, 2=d) ----------------
__global__ void cnt3_k(const int* e0, const int* e1, const int* e2,
                       int* __restrict__ cnt3, int NTp1) {
    int y = blockIdx.y;
    const int* ei = (y == 0) ? e0 : (y == 1) ? e1 : e2;
    int E = (y == 2) ? 640000 : 320000;
    int e = blockIdx.x * 256 + threadIdx.x;
    if (e < E) atomicAdd(&cnt3[y * NTp1 + ei[E + e]], 1);
}
__global__ __launch_bounds__(256) void scan_sum3_k(const int* __restrict__ cnt3,
                                                   int* __restrict__ bsum3, int NTp1) {
    __shared__ int wp[4];
    int y = blockIdx.y;
    int n = (y == 2) ? 40000 : 20000;
    int i = blockIdx.x * 256 + threadIdx.x;
    int lane = threadIdx.x & 63, wave = threadIdx.x >> 6;
    int v = (i < n) ? cnt3[y * NTp1 + i] : 0;
#pragma unroll
    for (int o = 32; o > 0; o >>= 1) v += __shfl_xor(v, o, 64);
    if (lane == 0) wp[wave] = v;
    __syncthreads();
    if (threadIdx.x == 0) bsum3[y * 256 + blockIdx.x] = wp[0] + wp[1] + wp[2] + wp[3];
}
__global__ __launch_bounds__(256) void scan_base3_k(int* __restrict__ bsum3,
                                                    int* rp0, int* rp1, int* rp2) {
    __shared__ int wp[4];
    int y = blockIdx.y;
    int n = (y == 2) ? 40000 : 20000;
    int nb = (n + 255) / 256;
    int* rp = (y == 0) ? rp0 : (y == 1) ? rp1 : rp2;
    int lane = threadIdx.x & 63, wave = threadIdx.x >> 6;
    int v = (threadIdx.x < nb) ? bsum3[y * 256 + threadIdx.x] : 0;
    int x = wscan_incl(v, lane);
    if (lane == 63) wp[wave] = x;
    __syncthreads();
    int off = 0;
#pragma unroll
    for (int w = 0; w < 4; ++w) off += (w < wave) ? wp[w] : 0;
    if (threadIdx.x < nb) bsum3[y * 256 + threadIdx.x] = off + x - v;
    if (threadIdx.x == 0) rp[n] = wp[0] + wp[1] + wp[2] + wp[3];
}
// also writes dinv for graphs 0,1 (dinv = rsqrt(indeg+1))
__global__ __launch_bounds__(256) void scan_fin3_k(const int* __restrict__ cnt3,
                                                   const int* __restrict__ bsum3,
                                                   int* rp0, int* rp1, int* rp2,
                                                   float* dv0, float* dv1, int NTp1) {
    __shared__ int wp[4];
    int y = blockIdx.y;
    int n = (y == 2) ? 40000 : 20000;
    int* rp = (y == 0) ? rp0 : (y == 1) ? rp1 : rp2;
    int i = blockIdx.x * 256 + threadIdx.x;
    int lane = threadIdx.x & 63, wave = threadIdx.x >> 6;
    int v = (i < n) ? cnt3[y * NTp1 + i] : 0;
    int x = wscan_incl(v, lane);
    if (lane == 63) wp[wave] = x;
    __syncthreads();
    int off = 0;
#pragma unroll
    for (int w = 0; w < 4; ++w) off += (w < wave) ? wp[w] : 0;
    if (i < n) {
        rp[i] = bsum3[y * 256 + blockIdx.x] + off + x - v;
        if (y == 0) dv0[i] = rsqrtf((float)(v + 1));
        else if (y == 1) dv1[i] = rsqrtf((float)(v + 1));
    }
}
// scatter using atomic decrement of the counts still in cnt3 (fills in reverse)
__global__ void scatter3_k(const int* e0, const int* e1, const int* e2,
                           const int* rp0, const int* rp1, const int* rp2,
                           int* __restrict__ cnt3,
                           int* c0, int* c1, int* c2, int NTp1) {
    int y = blockIdx.y;
    const int* ei = (y == 0) ? e0 : (y == 1) ? e1 : e2;
    const int* rp = (y == 0) ? rp0 : (y == 1) ? rp1 : rp2;
    int* col = (y == 0) ? c0 : (y == 1) ? c1 : c2;
    int E = (y == 2) ? 640000 : 320000;
    int e = blockIdx.x * 256 + threadIdx.x;
    if (e >= E) return;
    int s = ei[e], d = ei[E + e];
    int p = atomicAdd(&cnt3[y * NTp1 + d], -1) - 1;
    col[rp[d] + p] = s;
}

// ---------------- batched GCN GEMM (y = graph), LDS-free MR=1, frag-ordered B ----------
__global__ __launch_bounds__(256) void gemm2_k(const void* A0, const void* A1,
                                               const u16* __restrict__ Wtf0,
                                               const u16* __restrict__ Wtf1,
                                               const int* __restrict__ flagp,
                                               u16* __restrict__ C, int M) {
    int f = flagp[0];
    int y = blockIdx.y;
    const void* Aptr = y ? A1 : A0;
    const u16* Wtf = y ? Wtf1 : Wtf0;
    u16* Cp = C + (size_t)y * M * NF;
    int wave = threadIdx.x >> 6, lane = threadIdx.x & 63;
    int lr = lane & 15, q = lane >> 4;
    int arow = blockIdx.x * 64 + wave * 16 + lr;
    bool rok = arow < M;
    floatx4 acc[16];
#pragma unroll
    for (int nf = 0; nf < 16; ++nf) acc[nf] = (floatx4){0.f, 0.f, 0.f, 0.f};
    const u16* a16 = (const u16*)Aptr + (size_t)arow * NF;
    const float* a32 = (const float*)Aptr + (size_t)arow * NF;
#pragma unroll
    for (int ks = 0; ks < 8; ++ks) {
        int kk = ks * 32 + q * 8;
        union { u16 s[8]; uint4 u; short8 v; } a;
        if (!rok) {
            a.u = make_uint4(0u, 0u, 0u, 0u);
        } else if (f) {
            a.u = *(const uint4*)(a16 + kk);
            a.u.x = zap2(a.u.x); a.u.y = zap2(a.u.y);
            a.u.z = zap2(a.u.z); a.u.w = zap2(a.u.w);
        } else {
            float4 f0 = *(const float4*)(a32 + kk);
            float4 f1 = *(const float4*)(a32 + kk + 4);
            a.s[0] = f2bf(sane(f0.x)); a.s[1] = f2bf(sane(f0.y));
            a.s[2] = f2bf(sane(f0.z)); a.s[3] = f2bf(sane(f0.w));
            a.s[4] = f2bf(sane(f1.x)); a.s[5] = f2bf(sane(f1.y));
            a.s[6] = f2bf(sane(f1.z)); a.s[7] = f2bf(sane(f1.w));
        }
        const u16* bbase = Wtf + ks * 8192 + lane * 8;
#pragma unroll
        for (int nf = 0; nf < 16; ++nf) {
            short8 b = *(const short8*)(bbase + nf * 512);
            acc[nf] = __builtin_amdgcn_mfma_f32_16x16x32_bf16(a.v, b, acc[nf], 0, 0, 0);
        }
    }
#pragma unroll
    for (int nf = 0; nf < 16; ++nf) {
#pragma unroll
        for (int rr = 0; rr < 4; ++rr) {
            int gr = blockIdx.x * 64 + wave * 16 + q * 4 + rr;
            if (gr < M) Cp[(size_t)gr * NF + nf * 16 + lr] = f2bf(acc[nf][rr]);
        }
    }
}

// ---------------- GAT GEMM MR=1, fused scores epilogue (bf16 ws input) ----------------
__global__ __launch_bounds__(256) void gemm_gat_k(const u16* __restrict__ Aptr,
                                                  const u16* __restrict__ Wtf,
                                                  u16* __restrict__ C, int M,
                                                  const float* __restrict__ as_,
                                                  const float* __restrict__ ad_,
                                                  float* __restrict__ es,
                                                  float* __restrict__ ed) {
    int wave = threadIdx.x >> 6, lane = threadIdx.x & 63;
    int lr = lane & 15, q = lane >> 4;
    int arow = blockIdx.x * 64 + wave * 16 + lr;
    bool rok = arow < M;
    floatx4 acc[16];
#pragma unroll
    for (int nf = 0; nf < 16; ++nf) acc[nf] = (floatx4){0.f, 0.f, 0.f, 0.f};
    const u16* a16 = Aptr + (size_t)arow * NF;
#pragma unroll
    for (int ks = 0; ks < 8; ++ks) {
        int kk = ks * 32 + q * 8;
        union { uint4 u; short8 v; } a;
        a.u = rok ? *(const uint4*)(a16 + kk) : make_uint4(0u, 0u, 0u, 0u);
        const u16* bbase = Wtf + ks * 8192 + lane * 8;
#pragma unroll
        for (int nf = 0; nf < 16; ++nf) {
            short8 b = *(const short8*)(bbase + nf * 512);
            acc[nf] = __builtin_amdgcn_mfma_f32_16x16x32_bf16(a.v, b, acc[nf], 0, 0, 0);
        }
    }
#pragma unroll
    for (int nf = 0; nf < 16; ++nf) {
#pragma unroll
        for (int rr = 0; rr < 4; ++rr) {
            int gr = blockIdx.x * 64 + wave * 16 + q * 4 + rr;
            if (gr < M) C[(size_t)gr * NF + nf * 16 + lr] = f2bf(acc[nf][rr]);
        }
    }
    // fused scores (fp32 acc): s[row] = sum_c h[row][c]*a[c]
    float asl[16], adl[16];
#pragma unroll
    for (int nf = 0; nf < 16; ++nf) { asl[nf] = as_[nf * 16 + lr]; adl[nf] = ad_[nf * 16 + lr]; }
#pragma unroll
    for (int rr = 0; rr < 4; ++rr) {
        float s1 = 0.f, s2 = 0.f;
#pragma unroll
        for (int nf = 0; nf < 16; ++nf) {
            s1 += acc[nf][rr] * asl[nf];
            s2 += acc[nf][rr] * adl[nf];
        }
#pragma unroll
        for (int o = 1; o < 16; o <<= 1) {
            s1 += __shfl_xor(s1, o, 64);
            s2 += __shfl_xor(s2, o, 64);
        }
        int gr = blockIdx.x * 64 + wave * 16 + q * 4 + rr;
        if (lr == 0 && gr < M) { es[gr] = s1; ed[gr] = s2; }
    }
}

// ---------------- batched GCN aggregation via CSR (y = graph) ----------------
__global__ __launch_bounds__(256) void gcn_csr2_k(const u16* __restrict__ h,
                                                  const int* rp0, const int* rp1,
                                                  const int* c0, const int* c1,
                                                  const float* dv0, const float* dv1,
                                                  const float* __restrict__ prm,
                                                  u16* __restrict__ out, int n) {
    int y = blockIdx.y;
    const int* rp = y ? rp1 : rp0;
    const int* col = y ? c1 : c0;
    const float* dinv = y ? dv1 : dv0;
    const float* b = prm + (y ? P_BAGG : P_BGCN);
    const u16* hb = h + (size_t)y * n * NF;
    u16* ob = out + (size_t)y * n * NF;
    int wave = threadIdx.x >> 6, lane = threadIdx.x & 63;
    int i = blockIdx.x * 4 + wave;
    if (i >= n) return;
    int c = lane * 4;
    int beg = rp[i], end = rp[i + 1];
    float di = dinv[i];
    float4 hv = ld4h(hb + (size_t)i * NF + c);
    float w = di * di;
    float4 acc;
    acc.x = hv.x * w + b[c + 0];
    acc.y = hv.y * w + b[c + 1];
    acc.z = hv.z * w + b[c + 2];
    acc.w = hv.w * w + b[c + 3];
    int j = beg;
    for (; j + 3 < end; j += 4) {
        int s0 = col[j], s1 = col[j + 1], s2 = col[j + 2], s3 = col[j + 3];
        float n0 = dinv[s0] * di, n1 = dinv[s1] * di, n2 = dinv[s2] * di, n3 = dinv[s3] * di;
        float4 h0 = ld4h(hb + (size_t)s0 * NF + c);
        float4 h1 = ld4h(hb + (size_t)s1 * NF + c);
        float4 h2 = ld4h(hb + (size_t)s2 * NF + c);
        float4 h3 = ld4h(hb + (size_t)s3 * NF + c);
        acc.x += h0.x * n0 + h1.x * n1 + h2.x * n2 + h3.x * n3;
        acc.y += h0.y * n0 + h1.y * n1 + h2.y * n2 + h3.y * n3;
        acc.z += h0.z * n0 + h1.z * n1 + h2.z * n2 + h3.z * n3;
        acc.w += h0.w * n0 + h1.w * n1 + h2.w * n2 + h3.w * n3;
    }
    for (; j < end; ++j) {
        int s = col[j];
        float nrm = dinv[s] * di;
        float4 hs = ld4h(hb + (size_t)s * NF + c);
        acc.x += hs.x * nrm;
        acc.y += hs.y * nrm;
        acc.z += hs.z * nrm;
        acc.w += hs.w * nrm;
    }
    st4h(ob + (size_t)i * NF + c, acc);
}

// ---------------- BN partial stats (no atomics) ----------------
__global__ void bn_stats2_k(const u16* __restrict__ x, int n,
                            float* __restrict__ psum, float* __restrict__ psq) {
    int y = blockIdx.y;
    int c = threadIdx.x;  // 256
    int r0 = blockIdx.x * 128;
    int rend = min(r0 + 128, n);
    const u16* xb = x + (size_t)y * n * NF;
    float s = 0.f, qq = 0.f;
    for (int r = r0; r < rend; ++r) {
        float v = bf2f(xb[(size_t)r * NF + c]);
        s += v; qq += v * v;
    }
    size_t o = (size_t)(y * PB + blockIdx.x) * 512 + c;
    psum[o] = s; psq[o] = qq;
}
__global__ void bn_fin2_k(const float* __restrict__ psum, const float* __restrict__ psq,
                          float* __restrict__ stg, int n, int nb) {
    int y = blockIdx.y;
    int c = threadIdx.x;  // 256
    float s = 0.f, qq = 0.f;
    for (int b = 0; b < nb; ++b) {
        size_t o = (size_t)(y * PB + b) * 512 + c;
        s += psum[o]; qq += psq[o];
    }
    float inv_n = 1.0f / (float)n;
    float mean = s * inv_n;
    float var = fmaxf(qq * inv_n - mean * mean, 0.f);
    stg[y * 512 + c] = mean;
    stg[y * 512 + 256 + c] = rsqrtf(var + EPSV);
}
__global__ void bn_apply2_k(const u16* __restrict__ x, const float* __restrict__ stg,
                            const float* __restrict__ prm, u16* __restrict__ out, int n) {
    int y = blockIdx.y;
    int t = blockIdx.x * 256 + threadIdx.x;
    if (t >= n * NF) return;
    int c = t & 255;
    const float* st = stg + y * 512;
    const float* g = prm + (y ? P_AGG1 : P_G1);
    const float* be = prm + (y ? P_AGBE1 : P_BE1);
    float v = (bf2f(x[(size_t)y * n * NF + t]) - st[c]) * st[256 + c] * g[c] + be[c];
    out[(size_t)y * n * NF + t] = f2bf(fmaxf(v, 0.f));
}

// ---------------- single-pass fused GAT aggregation via CSR ----------------
// softmax without max-subtraction (scores are O(1): dots of O(1) activations with
// 1/sqrt(256)-scaled vectors; |e| << 88 so exp() cannot overflow). alpha = exp(e)/sum.
__global__ __launch_bounds__(256) void gat_csr_k(const u16* __restrict__ h,
                                                 const int* __restrict__ rp,
                                                 const int* __restrict__ col,
                                                 const float* __restrict__ es,
                                                 const float* __restrict__ ed,
                                                 const float* __restrict__ b,
                                                 u16* __restrict__ out, int n,
                                                 int do_relu) {
    int wave = threadIdx.x >> 6, lane = threadIdx.x & 63;
    int i = blockIdx.x * 4 + wave;
    if (i >= n) return;
    int beg = rp[i], end = rp[i + 1];
    float edi = ed[i];
    float ws = __expf(lrelu(es[i] + edi));
    int c = lane * 4;
    float4 hv = ld4h(h + (size_t)i * NF + c);
    float ssum = ws;
    float4 acc;
    acc.x = ws * hv.x; acc.y = ws * hv.y; acc.z = ws * hv.z; acc.w = ws * hv.w;
    int j = beg;
    for (; j + 3 < end; j += 4) {
        int s0 = col[j], s1 = col[j + 1], s2 = col[j + 2], s3 = col[j + 3];
        float4 h0 = ld4h(h + (size_t)s0 * NF + c);
        float4 h1 = ld4h(h + (size_t)s1 * NF + c);
        float4 h2 = ld4h(h + (size_t)s2 * NF + c);
        float4 h3 = ld4h(h + (size_t)s3 * NF + c);
        float a0 = __expf(lrelu(es[s0] + edi));
        float a1 = __expf(lrelu(es[s1] + edi));
        float a2 = __expf(lrelu(es[s2] + edi));
        float a3 = __expf(lrelu(es[s3] + edi));
        ssum += a0 + a1 + a2 + a3;
        acc.x += h0.x * a0 + h1.x * a1 + h2.x * a2 + h3.x * a3;
        acc.y += h0.y * a0 + h1.y * a1 + h2.y * a2 + h3.y * a3;
        acc.z += h0.z * a0 + h1.z * a1 + h2.z * a2 + h3.z * a3;
        acc.w += h0.w * a0 + h1.w * a1 + h2.w * a2 + h3.w * a3;
    }
    for (; j < end; ++j) {
        int s = col[j];
        float a = __expf(lrelu(es[s] + edi));
        float4 hs = ld4h(h + (size_t)s * NF + c);
        ssum += a;
        acc.x += a * hs.x;
        acc.y += a * hs.y;
        acc.z += a * hs.z;
        acc.w += a * hs.w;
    }
    float inv = 1.0f / ssum;
    acc.x = b[c + 0] + acc.x * inv;
    acc.y = b[c + 1] + acc.y * inv;
    acc.z = b[c + 2] + acc.z * inv;
    acc.w = b[c + 3] + acc.w * inv;
    if (do_relu) {
        acc.x = fmaxf(acc.x, 0.f); acc.y = fmaxf(acc.y, 0.f);
        acc.z = fmaxf(acc.z, 0.f); acc.w = fmaxf(acc.w, 0.f);
    }
    st4h(out + (size_t)i * NF + c, acc);
}

// ---------------- batched final-stage BN stats over cat(x,h) (512 ch) ----------------
__global__ void bn_stats_cat2_k(const u16* __restrict__ xp, const u16* __restrict__ hp,
                                int n, float* __restrict__ psum, float* __restrict__ psq) {
    int y = blockIdx.y;
    int c = threadIdx.x;  // 512
    int r0 = blockIdx.x * 128;
    int rend = min(r0 + 128, n);
    const u16* src = ((c < 256) ? xp : hp) + (size_t)y * n * NF;
    int cc = c & 255;
    float s = 0.f, qq = 0.f;
    for (int r = r0; r < rend; ++r) {
        float v = bf2f(src[(size_t)r * NF + cc]);
        s += v; qq += v * v;
    }
    size_t o = (size_t)(y * PB + blockIdx.x) * 512 + c;
    psum[o] = s; psq[o] = qq;
}
__global__ void bn_fin_cat2_k(const float* __restrict__ psum, const float* __restrict__ psq,
                              float* __restrict__ stc, int n, int nb) {
    int y = blockIdx.y;
    int c = threadIdx.x;  // 512
    float s = 0.f, qq = 0.f;
    for (int b = 0; b < nb; ++b) {
        size_t o = (size_t)(y * PB + b) * 512 + c;
        s += psum[o]; qq += psq[o];
    }
    float inv_n = 1.0f / (float)n;
    float mean = s * inv_n;
    float var = fmaxf(qq * inv_n - mean * mean, 0.f);
    stc[y * 1024 + c] = mean;
    stc[y * 1024 + 512 + c] = rsqrtf(var + EPSV);
}
__global__ void final2_k(const u16* __restrict__ xp, const u16* __restrict__ hp,
                         const float* __restrict__ stc, const float* __restrict__ prm,
                         float* __restrict__ out, int n) {
    int y = blockIdx.y;
    int wave = threadIdx.x >> 6, lane = threadIdx.x & 63;
    int i = blockIdx.x * 4 + wave;
    if (i >= n) return;
    const float* st = stc + y * 1024;
    const float* g = prm + (y ? P_AGG2 : P_G2);
    const float* be = prm + (y ? P_AGBE2 : P_BE2);
    const float* w = prm + (y ? P_WAGFC : P_WFC);
    float bias = prm[y ? P_BAGFC : P_BFC];
    const u16* src = (((lane < 32) ? xp : hp) + (size_t)y * n * NF) + (size_t)i * NF
                     + (lane < 32 ? lane * 8 : (lane - 32) * 8);
    uint4 u = *(const uint4*)src;
    float vv[8];
    vv[0] = bf2f((u16)(u.x & 0xFFFFu)); vv[1] = bf2f((u16)(u.x >> 16));
    vv[2] = bf2f((u16)(u.y & 0xFFFFu)); vv[3] = bf2f((u16)(u.y >> 16));
    vv[4] = bf2f((u16)(u.z & 0xFFFFu)); vv[5] = bf2f((u16)(u.z >> 16));
    vv[6] = bf2f((u16)(u.w & 0xFFFFu)); vv[7] = bf2f((u16)(u.w >> 16));
    int c0 = lane * 8;
    float acc = 0.f;
#pragma unroll
    for (int j = 0; j < 8; ++j) {
        int c = c0 + j;
        float v = (vv[j] - st[c]) * st[512 + c] * g[c] + be[c];
        v = fmaxf(v, 0.f);
        acc += v * w[c];
    }
    acc = wredsum(acc);
    if (lane == 0) out[(size_t)y * 20000 + i] = acc + bias;
}

// ---------------- host ----------------
extern "C" void kernel_launch(void* const* d_in, const int* in_sizes, int n_in,
                              void* d_out, int out_size, void* d_ws, size_t ws_size,
                              hipStream_t stream) {
    const void* x_ab = d_in[0];
    const void* x_ag = d_in[1];
    const int* e_ab = (const int*)d_in[26];
    const int* e_ag = (const int*)d_in[27];
    const int* e_d = (const int*)d_in[28];

    const int NAB = 20000, NT = 40000;
    const int EAB = 320000, EAG = 320000, ED = 640000;
    const int NTp1 = NT + 1;

    u16* hcat = (u16*)d_ws;                     // NT*NF u16
    u16* bufA = hcat + (size_t)NT * NF;         // NT*NF u16
    u16* bufB = bufA + (size_t)NT * NF;         // NT*NF u16
    u16* wt4 = bufB + (size_t)NT * NF;          // 4*65536 u16
    float* dv0 = (float*)(wt4 + 4 * 65536);     // NAB
    float* dv1 = dv0 + NAB;                     // NAB
    float* es = dv1 + NAB;                      // NT
    float* edv = es + NT;                       // NT
    float* stg = edv + NT;                      // 1024
    float* stc = stg + 1024;                    // 2048
    float* psum = stc + 2048;                   // 2*PB*512
    float* psq = psum + 2 * PB * 512;           // 2*PB*512
    float* prm = psq + 2 * PB * 512;            // 8192
    int* flag = (int*)(prm + 8192);             // 16
    int* rp_ab = flag + 16;                     // NAB+1
    int* rp_ag = rp_ab + NAB + 1;               // NAB+1
    int* rp_d = rp_ag + NAB + 1;                // NT+1
    int* cnt3 = rp_d + NT + 1;                  // 3*(NT+1)
    int* bsum3 = cnt3 + 3 * NTp1;               // 768
    int* col_ab = bsum3 + 768;                  // EAB
    int* col_ag = col_ab + EAB;                 // EAG
    int* col_d = col_ag + EAG;                  // ED

    u16* wt_gcn = wt4;
    u16* wt_aggcn = wt4 + 65536;
    u16* wt_gat = wt4 + 2 * 65536;
    u16* wt_gat2 = wt4 + 3 * 65536;

    dim3 t256(256), t512(512);
    const int nbg = (NAB + 127) / 128;   // 157 bn partial blocks per graph

    detect_k<<<dim3(1), t256, 0, stream>>>((const u16*)x_ab, flag);
    prep_k<<<dim3(1049), t256, 0, stream>>>(
        d_in[2], d_in[6], d_in[10], d_in[14],
        d_in[3], d_in[4], d_in[5], d_in[7], d_in[8], d_in[9],
        d_in[11], d_in[12], d_in[13], d_in[15], d_in[16], d_in[17],
        d_in[22], d_in[23], d_in[24], d_in[18], d_in[19], d_in[20],
        d_in[25], d_in[21], wt4, prm, cnt3, 3 * NTp1, flag);

    // batched CSR build (5 dispatches)
    cnt3_k<<<dim3(2500, 3), t256, 0, stream>>>(e_ab, e_ag, e_d, cnt3, NTp1);
    scan_sum3_k<<<dim3(157, 3), t256, 0, stream>>>(cnt3, bsum3, NTp1);
    scan_base3_k<<<dim3(1, 3), t256, 0, stream>>>(bsum3, rp_ab, rp_ag, rp_d);
    scan_fin3_k<<<dim3(157, 3), t256, 0, stream>>>(cnt3, bsum3, rp_ab, rp_ag, rp_d,
                                                   dv0, dv1, NTp1);
    scatter3_k<<<dim3(2500, 3), t256, 0, stream>>>(e_ab, e_ag, e_d, rp_ab, rp_ag, rp_d,
                                                   cnt3, col_ab, col_ag, col_d, NTp1);

    // batched GCN stage (5 dispatches)
    gemm2_k<<<dim3((NAB + 63) / 64, 2), t256, 0, stream>>>(x_ab, x_ag, wt_gcn, wt_aggcn,
                                                           flag, bufA, NAB);
    gcn_csr2_k<<<dim3((NAB + 3) / 4, 2), t256, 0, stream>>>(bufA, rp_ab, rp_ag,
                                                            col_ab, col_ag, dv0, dv1,
                                                            prm, bufB, NAB);
    bn_stats2_k<<<dim3(nbg, 2), t256, 0, stream>>>(bufB, NAB, psum, psq);
    bn_fin2_k<<<dim3(1, 2), t256, 0, stream>>>(psum, psq, stg, NAB, nbg);
    bn_apply2_k<<<dim3((NAB * NF + 255) / 256, 2), t256, 0, stream>>>(bufB, stg, prm,
                                                                      hcat, NAB);

    // GAT layer 1 (2 dispatches)
    gemm_gat_k<<<dim3((NT + 63) / 64), t256, 0, stream>>>(hcat, wt_gat, bufA, NT,
                                                          prm + P_ASRC, prm + P_ADST,
                                                          es, edv);
    gat_csr_k<<<dim3((NT + 3) / 4), t256, 0, stream>>>(bufA, rp_d, col_d, es, edv,
                                                       prm + P_BGAT, bufB, NT, 1);
    // GAT layer 2 (2 dispatches)
    gemm_gat_k<<<dim3((NT + 63) / 64), t256, 0, stream>>>(bufB, wt_gat2, bufA, NT,
                                                          prm + P_ASRC2, prm + P_ADST2,
                                                          es, edv);
    gat_csr_k<<<dim3((NT + 3) / 4), t256, 0, stream>>>(bufA, rp_d, col_d, es, edv,
                                                       prm + P_BGAT2, bufB, NT, 0);

    // batched final stage (3 dispatches)
    bn_stats_cat2_k<<<dim3(nbg, 2), t512, 0, stream>>>(bufB, hcat, NAB, psum, psq);
    bn_fin_cat2_k<<<dim3(1, 2), t512, 0, stream>>>(psum, psq, stc, NAB, nbg);
    final2_k<<<dim3((NAB + 3) / 4, 2), t256, 0, stream>>>(bufB, hcat, stc, prm,
                                                          (float*)d_out, NAB);
}

// Round 14
// 663.388 us; speedup vs baseline: 1.2112x; 1.0730x over previous
//
#include <hip/hip_runtime.h>
#include <hip/hip_bf16.h>
#include <stdint.h>

#define NF 256
#define EPSV 1e-5f
#define PB 160     // max bn partial blocks
#define MAXBUK 160 // max coarse buckets (dst>>8): 157 for NT=40000

typedef unsigned short u16;
typedef unsigned int u32;
typedef short short8 __attribute__((ext_vector_type(8)));
typedef float floatx4 __attribute__((ext_vector_type(4)));

// param block offsets (floats): 12 x 256, then 6 x 512, then 2 x 1
#define P_BGCN 0
#define P_G1 256
#define P_BE1 512
#define P_BAGG 768
#define P_AGG1 1024
#define P_AGBE1 1280
#define P_ASRC 1536
#define P_ADST 1792
#define P_BGAT 2048
#define P_ASRC2 2304
#define P_ADST2 2560
#define P_BGAT2 2816
#define P_G2 3072
#define P_BE2 3584
#define P_WFC 4096
#define P_AGG2 4608
#define P_AGBE2 5120
#define P_WAGFC 5632
#define P_BFC 6144
#define P_BAGFC 6145

__device__ __forceinline__ float bf2f(u16 u) {
    union { unsigned int i; float f; } v; v.i = ((unsigned int)u) << 16; return v.f;
}
__device__ __forceinline__ u16 f2bf(float f) {
    unsigned int x = __float_as_uint(f);
    unsigned int r = x + 0x7fffu + ((x >> 16) & 1u);
    return (u16)(r >> 16);
}
__device__ __forceinline__ float sane(float f) {
    return (f == f && fabsf(f) < 1e30f) ? f : 0.f;
}
__device__ __forceinline__ unsigned int zap2(unsigned int w) {
    if ((w & 0x00007F80u) == 0x00007F80u) w &= 0xFFFF0000u;
    if ((w & 0x7F800000u) == 0x7F800000u) w &= 0x0000FFFFu;
    return w;
}
__device__ __forceinline__ float lrelu(float x) { return x > 0.f ? x : 0.2f * x; }

__device__ __forceinline__ float4 ld4h(const u16* p) {
    uint2 u = *(const uint2*)p;
    float4 r;
    r.x = bf2f((u16)(u.x & 0xFFFFu)); r.y = bf2f((u16)(u.x >> 16));
    r.z = bf2f((u16)(u.y & 0xFFFFu)); r.w = bf2f((u16)(u.y >> 16));
    return r;
}
__device__ __forceinline__ void st4h(u16* p, float4 v) {
    uint2 u;
    u.x = (unsigned)f2bf(v.x) | ((unsigned)f2bf(v.y) << 16);
    u.y = (unsigned)f2bf(v.z) | ((unsigned)f2bf(v.w) << 16);
    *(uint2*)p = u;
}

__device__ __forceinline__ float wredsum(float v) {
#pragma unroll
    for (int o = 32; o > 0; o >>= 1) v += __shfl_xor(v, o, 64);
    return v;
}
__device__ __forceinline__ int wscan_incl(int x, int lane) {
#pragma unroll
    for (int o = 1; o < 64; o <<= 1) {
        int t = __shfl_up(x, o, 64);
        if (lane >= o) x += t;
    }
    return x;
}

// ---------------- dtype detect ----------------
__global__ void detect_k(const u16* __restrict__ x, int* __restrict__ flag) {
    __shared__ int cnt;
    if (threadIdx.x == 0) cnt = 0;
    __syncthreads();
    int c = 0;
#pragma unroll
    for (int k = 0; k < 4; ++k) {
        unsigned int u = x[2 * (threadIdx.x + 256 * k)];
        int e = (int)((u >> 7) & 0xFFu);
        if (u == 0u || (e >= 100 && e <= 140)) c++;
    }
    atomicAdd(&cnt, c);
    __syncthreads();
    if (threadIdx.x == 0) flag[0] = (cnt >= 512) ? 1 : 0;
}

// ---------------- prep: weight fragment-pack + param cvt + cnt3/gcur zero ----------------
__global__ void prep_k(const void* w0, const void* w1, const void* w2, const void* w3,
                       const void* p0, const void* p1, const void* p2, const void* p3,
                       const void* p4, const void* p5, const void* p6, const void* p7,
                       const void* p8, const void* p9, const void* p10, const void* p11,
                       const void* p12, const void* p13, const void* p14, const void* p15,
                       const void* p16, const void* p17, const void* p18, const void* p19,
                       u16* __restrict__ wtf, float* __restrict__ prm,
                       int* __restrict__ cnt3, int ncnt,
                       const int* __restrict__ flagp) {
    int f = flagp[0];
    int idx = blockIdx.x * 256 + threadIdx.x;
    if (idx < ncnt) cnt3[idx] = 0;
    if (idx < 262144) {
        const void* ws[4] = {w0, w1, w2, w3};
        int wi = idx >> 16;
        int rest = idx & 65535;
        int j = rest & 7;
        int lr = (rest >> 3) & 15;
        int q = (rest >> 7) & 3;
        int nf = (rest >> 9) & 15;
        int ks = (rest >> 13) & 7;
        int n = nf * 16 + lr;
        int k = ks * 32 + q * 8 + j;
        const void* W = ws[wi];
        u16 v;
        if (f) {
            v = ((const u16*)W)[k * NF + n];
            if ((v & 0x7F80u) == 0x7F80u) v = 0;
        } else {
            v = f2bf(sane(((const float*)W)[k * NF + n]));
        }
        wtf[idx] = v;
        return;
    }
    int pidx = idx - 262144;
    if (pidx >= 6146) return;
    const void* ptrs[20] = {p0, p1, p2, p3, p4, p5, p6, p7, p8, p9,
                            p10, p11, p12, p13, p14, p15, p16, p17, p18, p19};
    int t, j;
    if (pidx < 3072) { t = pidx >> 8; j = pidx & 255; }
    else if (pidx < 6144) { t = 12 + ((pidx - 3072) >> 9); j = (pidx - 3072) & 511; }
    else { t = 18 + (pidx - 6144); j = 0; }
    float v = f ? bf2f(((const u16*)ptrs[t])[j]) : ((const float*)ptrs[t])[j];
    prm[pidx] = sane(v);
}

// ---------------- batched CSR build (y = graph: 0=ab, 1=ag, 2=d) ----------------
__global__ void cnt3_k(const int* e0, const int* e1, const int* e2,
                       int* __restrict__ cnt3, int NTp1) {
    int y = blockIdx.y;
    const int* ei = (y == 0) ? e0 : (y == 1) ? e1 : e2;
    int E = (y == 2) ? 640000 : 320000;
    int e = blockIdx.x * 256 + threadIdx.x;
    if (e < E) atomicAdd(&cnt3[y * NTp1 + ei[E + e]], 1);
}
__global__ __launch_bounds__(256) void scan_sum3_k(const int* __restrict__ cnt3,
                                                   int* __restrict__ bsum3, int NTp1) {
    __shared__ int wp[4];
    int y = blockIdx.y;
    int n = (y == 2) ? 40000 : 20000;
    int i = blockIdx.x * 256 + threadIdx.x;
    int lane = threadIdx.x & 63, wave = threadIdx.x >> 6;
    int v = (i < n) ? cnt3[y * NTp1 + i] : 0;
#pragma unroll
    for (int o = 32; o > 0; o >>= 1) v += __shfl_xor(v, o, 64);
    if (lane == 0) wp[wave] = v;
    __syncthreads();
    if (threadIdx.x == 0) bsum3[y * 256 + blockIdx.x] = wp[0] + wp[1] + wp[2] + wp[3];
}
__global__ __launch_bounds__(256) void scan_base3_k(int* __restrict__ bsum3,
                                                    int* rp0, int* rp1, int* rp2) {
    __shared__ int wp[4];
    int y = blockIdx.y;
    int n = (y == 2) ? 40000 : 20000;
    int nb = (n + 255) / 256;
    int* rp = (y == 0) ? rp0 : (y == 1) ? rp1 : rp2;
    int lane = threadIdx.x & 63, wave = threadIdx.x >> 6;
    int v = (threadIdx.x < nb) ? bsum3[y * 256 + threadIdx.x] : 0;
    int x = wscan_incl(v, lane);
    if (lane == 63) wp[wave] = x;
    __syncthreads();
    int off = 0;
#pragma unroll
    for (int w = 0; w < 4; ++w) off += (w < wave) ? wp[w] : 0;
    if (threadIdx.x < nb) bsum3[y * 256 + threadIdx.x] = off + x - v;
    if (threadIdx.x == 0) rp[n] = wp[0] + wp[1] + wp[2] + wp[3];
}
// also writes dinv for graphs 0,1 (dinv = rsqrt(indeg+1))
__global__ __launch_bounds__(256) void scan_fin3_k(const int* __restrict__ cnt3,
                                                   const int* __restrict__ bsum3,
                                                   int* rp0, int* rp1, int* rp2,
                                                   float* dv0, float* dv1, int NTp1) {
    __shared__ int wp[4];
    int y = blockIdx.y;
    int n = (y == 2) ? 40000 : 20000;
    int* rp = (y == 0) ? rp0 : (y == 1) ? rp1 : rp2;
    int i = blockIdx.x * 256 + threadIdx.x;
    int lane = threadIdx.x & 63, wave = threadIdx.x >> 6;
    int v = (i < n) ? cnt3[y * NTp1 + i] : 0;
    int x = wscan_incl(v, lane);
    if (lane == 63) wp[wave] = x;
    __syncthreads();
    int off = 0;
#pragma unroll
    for (int w = 0; w < 4; ++w) off += (w < wave) ? wp[w] : 0;
    if (i < n) {
        rp[i] = bsum3[y * 256 + blockIdx.x] + off + x - v;
        if (y == 0) dv0[i] = rsqrtf((float)(v + 1));
        else if (y == 1) dv1[i] = rsqrtf((float)(v + 1));
    }
}

// ---------------- locality-binned scatter, pass A: bucket-binned staging ----------------
// bucket b = dst>>8 (256-dst ranges). Staging record = src | (dst&255)<<16 (4B).
// Staging region of bucket b is [rp[b<<8], rp[min((b+1)<<8,n)]) — same space as col.
__global__ __launch_bounds__(256) void bin3_k(const int* e0, const int* e1, const int* e2,
                                              const int* rp0, const int* rp1, const int* rp2,
                                              int* __restrict__ gcur,
                                              u32* s0, u32* s1, u32* s2, int NTp1) {
    int y = blockIdx.y;
    const int* ei = (y == 0) ? e0 : (y == 1) ? e1 : e2;
    const int* rp = (y == 0) ? rp0 : (y == 1) ? rp1 : rp2;
    u32* stg = (y == 0) ? s0 : (y == 1) ? s1 : s2;
    int E = (y == 2) ? 640000 : 320000;
    int n = (y == 2) ? 40000 : 20000;
    int nbuk = (n + 255) >> 8;
    int base = blockIdx.x * 4096;
    if (base >= E) return;
    __shared__ int lcnt[MAXBUK];
    __shared__ int lbase[MAXBUK];
    if (threadIdx.x < nbuk) lcnt[threadIdx.x] = 0;
    __syncthreads();
#pragma unroll
    for (int t = 0; t < 16; ++t) {
        int e = base + t * 256 + threadIdx.x;
        if (e < E) atomicAdd(&lcnt[ei[E + e] >> 8], 1);
    }
    __syncthreads();
    if (threadIdx.x < nbuk) {
        int cnt = lcnt[threadIdx.x];
        int g = cnt ? atomicAdd(&gcur[y * MAXBUK + threadIdx.x], cnt) : 0;
        lbase[threadIdx.x] = rp[threadIdx.x << 8] + g;
        lcnt[threadIdx.x] = 0;
    }
    __syncthreads();
#pragma unroll
    for (int t = 0; t < 16; ++t) {
        int e = base + t * 256 + threadIdx.x;
        if (e < E) {
            int s = ei[e], d = ei[E + e];
            int b = d >> 8;
            int r = atomicAdd(&lcnt[b], 1);
            stg[lbase[b] + r] = (u32)s | ((u32)(d & 255) << 16);
        }
    }
}
// pass B: one block owns one bucket; rank per dst via LDS; col writes confined to ~16KB
__global__ __launch_bounds__(256) void place3_k(const u32* s0, const u32* s1, const u32* s2,
                                                const int* rp0, const int* rp1, const int* rp2,
                                                int* c0, int* c1, int* c2) {
    int y = blockIdx.y;
    int b = blockIdx.x;
    int n = (y == 2) ? 40000 : 20000;
    int nbuk = (n + 255) >> 8;
    if (b >= nbuk) return;
    const u32* stg = (y == 0) ? s0 : (y == 1) ? s1 : s2;
    const int* rp = (y == 0) ? rp0 : (y == 1) ? rp1 : rp2;
    int* col = (y == 0) ? c0 : (y == 1) ? c1 : c2;
    int d0 = b << 8;
    int dn = min(256, n - d0);
    __shared__ int lrp[257];
    __shared__ int lcnt[256];
    if (threadIdx.x < dn) lrp[threadIdx.x] = rp[d0 + threadIdx.x];
    if (threadIdx.x == 0) lrp[dn] = rp[d0 + dn];
    lcnt[threadIdx.x] = 0;
    __syncthreads();
    int beg = lrp[0], end = lrp[dn];
    for (int j = beg + threadIdx.x; j < end; j += 256) {
        u32 v = stg[j];
        int dl = (int)(v >> 16);
        int s = (int)(v & 0xFFFFu);
        int r = atomicAdd(&lcnt[dl], 1);
        col[lrp[dl] + r] = s;
    }
}

// ---------------- batched GCN GEMM (y = graph), LDS-free MR=1, frag-ordered B ----------
__global__ __launch_bounds__(256) void gemm2_k(const void* A0, const void* A1,
                                               const u16* __restrict__ Wtf0,
                                               const u16* __restrict__ Wtf1,
                                               const int* __restrict__ flagp,
                                               u16* __restrict__ C, int M) {
    int f = flagp[0];
    int y = blockIdx.y;
    const void* Aptr = y ? A1 : A0;
    const u16* Wtf = y ? Wtf1 : Wtf0;
    u16* Cp = C + (size_t)y * M * NF;
    int wave = threadIdx.x >> 6, lane = threadIdx.x & 63;
    int lr = lane & 15, q = lane >> 4;
    int arow = blockIdx.x * 64 + wave * 16 + lr;
    bool rok = arow < M;
    floatx4 acc[16];
#pragma unroll
    for (int nf = 0; nf < 16; ++nf) acc[nf] = (floatx4){0.f, 0.f, 0.f, 0.f};
    const u16* a16 = (const u16*)Aptr + (size_t)arow * NF;
    const float* a32 = (const float*)Aptr + (size_t)arow * NF;
#pragma unroll
    for (int ks = 0; ks < 8; ++ks) {
        int kk = ks * 32 + q * 8;
        union { u16 s[8]; uint4 u; short8 v; } a;
        if (!rok) {
            a.u = make_uint4(0u, 0u, 0u, 0u);
        } else if (f) {
            a.u = *(const uint4*)(a16 + kk);
            a.u.x = zap2(a.u.x); a.u.y = zap2(a.u.y);
            a.u.z = zap2(a.u.z); a.u.w = zap2(a.u.w);
        } else {
            float4 f0 = *(const float4*)(a32 + kk);
            float4 f1 = *(const float4*)(a32 + kk + 4);
            a.s[0] = f2bf(sane(f0.x)); a.s[1] = f2bf(sane(f0.y));
            a.s[2] = f2bf(sane(f0.z)); a.s[3] = f2bf(sane(f0.w));
            a.s[4] = f2bf(sane(f1.x)); a.s[5] = f2bf(sane(f1.y));
            a.s[6] = f2bf(sane(f1.z)); a.s[7] = f2bf(sane(f1.w));
        }
        const u16* bbase = Wtf + ks * 8192 + lane * 8;
#pragma unroll
        for (int nf = 0; nf < 16; ++nf) {
            short8 b = *(const short8*)(bbase + nf * 512);
            acc[nf] = __builtin_amdgcn_mfma_f32_16x16x32_bf16(a.v, b, acc[nf], 0, 0, 0);
        }
    }
#pragma unroll
    for (int nf = 0; nf < 16; ++nf) {
#pragma unroll
        for (int rr = 0; rr < 4; ++rr) {
            int gr = blockIdx.x * 64 + wave * 16 + q * 4 + rr;
            if (gr < M) Cp[(size_t)gr * NF + nf * 16 + lr] = f2bf(acc[nf][rr]);
        }
    }
}

// ---------------- GAT GEMM MR=1, fused scores epilogue (bf16 ws input) ----------------
__global__ __launch_bounds__(256) void gemm_gat_k(const u16* __restrict__ Aptr,
                                                  const u16* __restrict__ Wtf,
                                                  u16* __restrict__ C, int M,
                                                  const float* __restrict__ as_,
                                                  const float* __restrict__ ad_,
                                                  float* __restrict__ es,
                                                  float* __restrict__ ed) {
    int wave = threadIdx.x >> 6, lane = threadIdx.x & 63;
    int lr = lane & 15, q = lane >> 4;
    int arow = blockIdx.x * 64 + wave * 16 + lr;
    bool rok = arow < M;
    floatx4 acc[16];
#pragma unroll
    for (int nf = 0; nf < 16; ++nf) acc[nf] = (floatx4){0.f, 0.f, 0.f, 0.f};
    const u16* a16 = Aptr + (size_t)arow * NF;
#pragma unroll
    for (int ks = 0; ks < 8; ++ks) {
        int kk = ks * 32 + q * 8;
        union { uint4 u; short8 v; } a;
        a.u = rok ? *(const uint4*)(a16 + kk) : make_uint4(0u, 0u, 0u, 0u);
        const u16* bbase = Wtf + ks * 8192 + lane * 8;
#pragma unroll
        for (int nf = 0; nf < 16; ++nf) {
            short8 b = *(const short8*)(bbase + nf * 512);
            acc[nf] = __builtin_amdgcn_mfma_f32_16x16x32_bf16(a.v, b, acc[nf], 0, 0, 0);
        }
    }
#pragma unroll
    for (int nf = 0; nf < 16; ++nf) {
#pragma unroll
        for (int rr = 0; rr < 4; ++rr) {
            int gr = blockIdx.x * 64 + wave * 16 + q * 4 + rr;
            if (gr < M) C[(size_t)gr * NF + nf * 16 + lr] = f2bf(acc[nf][rr]);
        }
    }
    float asl[16], adl[16];
#pragma unroll
    for (int nf = 0; nf < 16; ++nf) { asl[nf] = as_[nf * 16 + lr]; adl[nf] = ad_[nf * 16 + lr]; }
#pragma unroll
    for (int rr = 0; rr < 4; ++rr) {
        float s1 = 0.f, s2 = 0.f;
#pragma unroll
        for (int nf = 0; nf < 16; ++nf) {
            s1 += acc[nf][rr] * asl[nf];
            s2 += acc[nf][rr] * adl[nf];
        }
#pragma unroll
        for (int o = 1; o < 16; o <<= 1) {
            s1 += __shfl_xor(s1, o, 64);
            s2 += __shfl_xor(s2, o, 64);
        }
        int gr = blockIdx.x * 64 + wave * 16 + q * 4 + rr;
        if (lr == 0 && gr < M) { es[gr] = s1; ed[gr] = s2; }
    }
}

// ---------------- batched GCN aggregation via CSR (y = graph) ----------------
__global__ __launch_bounds__(256) void gcn_csr2_k(const u16* __restrict__ h,
                                                  const int* rp0, const int* rp1,
                                                  const int* c0, const int* c1,
                                                  const float* dv0, const float* dv1,
                                                  const float* __restrict__ prm,
                                                  u16* __restrict__ out, int n) {
    int y = blockIdx.y;
    const int* rp = y ? rp1 : rp0;
    const int* col = y ? c1 : c0;
    const float* dinv = y ? dv1 : dv0;
    const float* b = prm + (y ? P_BAGG : P_BGCN);
    const u16* hb = h + (size_t)y * n * NF;
    u16* ob = out + (size_t)y * n * NF;
    int wave = threadIdx.x >> 6, lane = threadIdx.x & 63;
    int i = blockIdx.x * 4 + wave;
    if (i >= n) return;
    int c = lane * 4;
    int beg = rp[i], end = rp[i + 1];
    float di = dinv[i];
    float4 hv = ld4h(hb + (size_t)i * NF + c);
    float w = di * di;
    float4 acc;
    acc.x = hv.x * w + b[c + 0];
    acc.y = hv.y * w + b[c + 1];
    acc.z = hv.z * w + b[c + 2];
    acc.w = hv.w * w + b[c + 3];
    int j = beg;
    for (; j + 3 < end; j += 4) {
        int s0 = col[j], s1 = col[j + 1], s2 = col[j + 2], s3 = col[j + 3];
        float n0 = dinv[s0] * di, n1 = dinv[s1] * di, n2 = dinv[s2] * di, n3 = dinv[s3] * di;
        float4 h0 = ld4h(hb + (size_t)s0 * NF + c);
        float4 h1 = ld4h(hb + (size_t)s1 * NF + c);
        float4 h2 = ld4h(hb + (size_t)s2 * NF + c);
        float4 h3 = ld4h(hb + (size_t)s3 * NF + c);
        acc.x += h0.x * n0 + h1.x * n1 + h2.x * n2 + h3.x * n3;
        acc.y += h0.y * n0 + h1.y * n1 + h2.y * n2 + h3.y * n3;
        acc.z += h0.z * n0 + h1.z * n1 + h2.z * n2 + h3.z * n3;
        acc.w += h0.w * n0 + h1.w * n1 + h2.w * n2 + h3.w * n3;
    }
    for (; j < end; ++j) {
        int s = col[j];
        float nrm = dinv[s] * di;
        float4 hs = ld4h(hb + (size_t)s * NF + c);
        acc.x += hs.x * nrm;
        acc.y += hs.y * nrm;
        acc.z += hs.z * nrm;
        acc.w += hs.w * nrm;
    }
    st4h(ob + (size_t)i * NF + c, acc);
}

// ---------------- BN partial stats (no atomics) ----------------
__global__ void bn_stats2_k(const u16* __restrict__ x, int n,
                            float* __restrict__ psum, float* __restrict__ psq) {
    int y = blockIdx.y;
    int c = threadIdx.x;  // 256
    int r0 = blockIdx.x * 128;
    int rend = min(r0 + 128, n);
    const u16* xb = x + (size_t)y * n * NF;
    float s = 0.f, qq = 0.f;
    for (int r = r0; r < rend; ++r) {
        float v = bf2f(xb[(size_t)r * NF + c]);
        s += v; qq += v * v;
    }
    size_t o = (size_t)(y * PB + blockIdx.x) * 512 + c;
    psum[o] = s; psq[o] = qq;
}
__global__ void bn_fin2_k(const float* __restrict__ psum, const float* __restrict__ psq,
                          float* __restrict__ stg, int n, int nb) {
    int y = blockIdx.y;
    int c = threadIdx.x;  // 256
    float s = 0.f, qq = 0.f;
    for (int b = 0; b < nb; ++b) {
        size_t o = (size_t)(y * PB + b) * 512 + c;
        s += psum[o]; qq += psq[o];
    }
    float inv_n = 1.0f / (float)n;
    float mean = s * inv_n;
    float var = fmaxf(qq * inv_n - mean * mean, 0.f);
    stg[y * 512 + c] = mean;
    stg[y * 512 + 256 + c] = rsqrtf(var + EPSV);
}
__global__ void bn_apply2_k(const u16* __restrict__ x, const float* __restrict__ stg,
                            const float* __restrict__ prm, u16* __restrict__ out, int n) {
    int y = blockIdx.y;
    int t = blockIdx.x * 256 + threadIdx.x;
    if (t >= n * NF) return;
    int c = t & 255;
    const float* st = stg + y * 512;
    const float* g = prm + (y ? P_AGG1 : P_G1);
    const float* be = prm + (y ? P_AGBE1 : P_BE1);
    float v = (bf2f(x[(size_t)y * n * NF + t]) - st[c]) * st[256 + c] * g[c] + be[c];
    out[(size_t)y * n * NF + t] = f2bf(fmaxf(v, 0.f));
}

// ---------------- single-pass fused GAT aggregation via CSR ----------------
__global__ __launch_bounds__(256) void gat_csr_k(const u16* __restrict__ h,
                                                 const int* __restrict__ rp,
                                                 const int* __restrict__ col,
                                                 const float* __restrict__ es,
                                                 const float* __restrict__ ed,
                                                 const float* __restrict__ b,
                                                 u16* __restrict__ out, int n,
                                                 int do_relu) {
    int wave = threadIdx.x >> 6, lane = threadIdx.x & 63;
    int i = blockIdx.x * 4 + wave;
    if (i >= n) return;
    int beg = rp[i], end = rp[i + 1];
    float edi = ed[i];
    float ws = __expf(lrelu(es[i] + edi));
    int c = lane * 4;
    float4 hv = ld4h(h + (size_t)i * NF + c);
    float ssum = ws;
    float4 acc;
    acc.x = ws * hv.x; acc.y = ws * hv.y; acc.z = ws * hv.z; acc.w = ws * hv.w;
    int j = beg;
    for (; j + 3 < end; j += 4) {
        int s0 = col[j], s1 = col[j + 1], s2 = col[j + 2], s3 = col[j + 3];
        float4 h0 = ld4h(h + (size_t)s0 * NF + c);
        float4 h1 = ld4h(h + (size_t)s1 * NF + c);
        float4 h2 = ld4h(h + (size_t)s2 * NF + c);
        float4 h3 = ld4h(h + (size_t)s3 * NF + c);
        float a0 = __expf(lrelu(es[s0] + edi));
        float a1 = __expf(lrelu(es[s1] + edi));
        float a2 = __expf(lrelu(es[s2] + edi));
        float a3 = __expf(lrelu(es[s3] + edi));
        ssum += a0 + a1 + a2 + a3;
        acc.x += h0.x * a0 + h1.x * a1 + h2.x * a2 + h3.x * a3;
        acc.y += h0.y * a0 + h1.y * a1 + h2.y * a2 + h3.y * a3;
        acc.z += h0.z * a0 + h1.z * a1 + h2.z * a2 + h3.z * a3;
        acc.w += h0.w * a0 + h1.w * a1 + h2.w * a2 + h3.w * a3;
    }
    for (; j < end; ++j) {
        int s = col[j];
        float a = __expf(lrelu(es[s] + edi));
        float4 hs = ld4h(h + (size_t)s * NF + c);
        ssum += a;
        acc.x += a * hs.x;
        acc.y += a * hs.y;
        acc.z += a * hs.z;
        acc.w += a * hs.w;
    }
    float inv = 1.0f / ssum;
    acc.x = b[c + 0] + acc.x * inv;
    acc.y = b[c + 1] + acc.y * inv;
    acc.z = b[c + 2] + acc.z * inv;
    acc.w = b[c + 3] + acc.w * inv;
    if (do_relu) {
        acc.x = fmaxf(acc.x, 0.f); acc.y = fmaxf(acc.y, 0.f);
        acc.z = fmaxf(acc.z, 0.f); acc.w = fmaxf(acc.w, 0.f);
    }
    st4h(out + (size_t)i * NF + c, acc);
}

// ---------------- batched final-stage BN stats over cat(x,h) (512 ch) ----------------
__global__ void bn_stats_cat2_k(const u16* __restrict__ xp, const u16* __restrict__ hp,
                                int n, float* __restrict__ psum, float* __restrict__ psq) {
    int y = blockIdx.y;
    int c = threadIdx.x;  // 512
    int r0 = blockIdx.x * 128;
    int rend = min(r0 + 128, n);
    const u16* src = ((c < 256) ? xp : hp) + (size_t)y * n * NF;
    int cc = c & 255;
    float s = 0.f, qq = 0.f;
    for (int r = r0; r < rend; ++r) {
        float v = bf2f(src[(size_t)r * NF + cc]);
        s += v; qq += v * v;
    }
    size_t o = (size_t)(y * PB + blockIdx.x) * 512 + c;
    psum[o] = s; psq[o] = qq;
}
__global__ void bn_fin_cat2_k(const float* __restrict__ psum, const float* __restrict__ psq,
                              float* __restrict__ stc, int n, int nb) {
    int y = blockIdx.y;
    int c = threadIdx.x;  // 512
    float s = 0.f, qq = 0.f;
    for (int b = 0; b < nb; ++b) {
        size_t o = (size_t)(y * PB + b) * 512 + c;
        s += psum[o]; qq += psq[o];
    }
    float inv_n = 1.0f / (float)n;
    float mean = s * inv_n;
    float var = fmaxf(qq * inv_n - mean * mean, 0.f);
    stc[y * 1024 + c] = mean;
    stc[y * 1024 + 512 + c] = rsqrtf(var + EPSV);
}
__global__ void final2_k(const u16* __restrict__ xp, const u16* __restrict__ hp,
                         const float* __restrict__ stc, const float* __restrict__ prm,
                         float* __restrict__ out, int n) {
    int y = blockIdx.y;
    int wave = threadIdx.x >> 6, lane = threadIdx.x & 63;
    int i = blockIdx.x * 4 + wave;
    if (i >= n) return;
    const float* st = stc + y * 1024;
    const float* g = prm + (y ? P_AGG2 : P_G2);
    const float* be = prm + (y ? P_AGBE2 : P_BE2);
    const float* w = prm + (y ? P_WAGFC : P_WFC);
    float bias = prm[y ? P_BAGFC : P_BFC];
    const u16* src = (((lane < 32) ? xp : hp) + (size_t)y * n * NF) + (size_t)i * NF
                     + (lane < 32 ? lane * 8 : (lane - 32) * 8);
    uint4 u = *(const uint4*)src;
    float vv[8];
    vv[0] = bf2f((u16)(u.x & 0xFFFFu)); vv[1] = bf2f((u16)(u.x >> 16));
    vv[2] = bf2f((u16)(u.y & 0xFFFFu)); vv[3] = bf2f((u16)(u.y >> 16));
    vv[4] = bf2f((u16)(u.z & 0xFFFFu)); vv[5] = bf2f((u16)(u.z >> 16));
    vv[6] = bf2f((u16)(u.w & 0xFFFFu)); vv[7] = bf2f((u16)(u.w >> 16));
    int c0 = lane * 8;
    float acc = 0.f;
#pragma unroll
    for (int j = 0; j < 8; ++j) {
        int c = c0 + j;
        float v = (vv[j] - st[c]) * st[512 + c] * g[c] + be[c];
        v = fmaxf(v, 0.f);
        acc += v * w[c];
    }
    acc = wredsum(acc);
    if (lane == 0) out[(size_t)y * 20000 + i] = acc + bias;
}

// ---------------- host ----------------
extern "C" void kernel_launch(void* const* d_in, const int* in_sizes, int n_in,
                              void* d_out, int out_size, void* d_ws, size_t ws_size,
                              hipStream_t stream) {
    const void* x_ab = d_in[0];
    const void* x_ag = d_in[1];
    const int* e_ab = (const int*)d_in[26];
    const int* e_ag = (const int*)d_in[27];
    const int* e_d = (const int*)d_in[28];

    const int NAB = 20000, NT = 40000;
    const int EAB = 320000, EAG = 320000, ED = 640000;
    const int NTp1 = NT + 1;

    u16* hcat = (u16*)d_ws;                     // NT*NF u16
    u16* bufA = hcat + (size_t)NT * NF;         // NT*NF u16
    u16* bufB = bufA + (size_t)NT * NF;         // NT*NF u16
    u16* wt4 = bufB + (size_t)NT * NF;          // 4*65536 u16
    float* dv0 = (float*)(wt4 + 4 * 65536);     // NAB
    float* dv1 = dv0 + NAB;                     // NAB
    float* es = dv1 + NAB;                      // NT
    float* edv = es + NT;                       // NT
    float* stg2 = edv + NT;                     // 1024 (bn stage stats)
    float* stc = stg2 + 1024;                   // 2048
    float* psum = stc + 2048;                   // 2*PB*512
    float* psq = psum + 2 * PB * 512;           // 2*PB*512
    float* prm = psq + 2 * PB * 512;            // 8192
    int* flag = (int*)(prm + 8192);             // 16
    int* rp_ab = flag + 16;                     // NAB+1
    int* rp_ag = rp_ab + NAB + 1;               // NAB+1
    int* rp_d = rp_ag + NAB + 1;                // NT+1
    int* cnt3 = rp_d + NT + 1;                  // 3*(NT+1)
    int* gcur = cnt3 + 3 * NTp1;                // 3*MAXBUK
    int* bsum3 = gcur + 3 * MAXBUK;             // 768
    int* col_ab = bsum3 + 768;                  // EAB
    int* col_ag = col_ab + EAB;                 // EAG
    int* col_d = col_ag + EAG;                  // ED
    u32* stg_ab = (u32*)(col_d + ED);           // EAB
    u32* stg_ag = stg_ab + EAB;                 // EAG
    u32* stg_d = stg_ag + EAG;                  // ED

    u16* wt_gcn = wt4;
    u16* wt_aggcn = wt4 + 65536;
    u16* wt_gat = wt4 + 2 * 65536;
    u16* wt_gat2 = wt4 + 3 * 65536;

    dim3 t256(256), t512(512);
    const int nbg = (NAB + 127) / 128;   // 157 bn partial blocks per graph

    detect_k<<<dim3(1), t256, 0, stream>>>((const u16*)x_ab, flag);
    prep_k<<<dim3(1049), t256, 0, stream>>>(
        d_in[2], d_in[6], d_in[10], d_in[14],
        d_in[3], d_in[4], d_in[5], d_in[7], d_in[8], d_in[9],
        d_in[11], d_in[12], d_in[13], d_in[15], d_in[16], d_in[17],
        d_in[22], d_in[23], d_in[24], d_in[18], d_in[19], d_in[20],
        d_in[25], d_in[21], wt4, prm, cnt3, 3 * NTp1 + 3 * MAXBUK, flag);

    // batched CSR build (6 dispatches, locality-binned scatter)
    cnt3_k<<<dim3(2500, 3), t256, 0, stream>>>(e_ab, e_ag, e_d, cnt3, NTp1);
    scan_sum3_k<<<dim3(157, 3), t256, 0, stream>>>(cnt3, bsum3, NTp1);
    scan_base3_k<<<dim3(1, 3), t256, 0, stream>>>(bsum3, rp_ab, rp_ag, rp_d);
    scan_fin3_k<<<dim3(157, 3), t256, 0, stream>>>(cnt3, bsum3, rp_ab, rp_ag, rp_d,
                                                   dv0, dv1, NTp1);
    bin3_k<<<dim3(157, 3), t256, 0, stream>>>(e_ab, e_ag, e_d, rp_ab, rp_ag, rp_d,
                                              gcur, stg_ab, stg_ag, stg_d, NTp1);
    place3_k<<<dim3(157, 3), t256, 0, stream>>>(stg_ab, stg_ag, stg_d,
                                                rp_ab, rp_ag, rp_d,
                                                col_ab, col_ag, col_d);

    // batched GCN stage (5 dispatches)
    gemm2_k<<<dim3((NAB + 63) / 64, 2), t256, 0, stream>>>(x_ab, x_ag, wt_gcn, wt_aggcn,
                                                           flag, bufA, NAB);
    gcn_csr2_k<<<dim3((NAB + 3) / 4, 2), t256, 0, stream>>>(bufA, rp_ab, rp_ag,
                                                            col_ab, col_ag, dv0, dv1,
                                                            prm, bufB, NAB);
    bn_stats2_k<<<dim3(nbg, 2), t256, 0, stream>>>(bufB, NAB, psum, psq);
    bn_fin2_k<<<dim3(1, 2), t256, 0, stream>>>(psum, psq, stg2, NAB, nbg);
    bn_apply2_k<<<dim3((NAB * NF + 255) / 256, 2), t256, 0, stream>>>(bufB, stg2, prm,
                                                                      hcat, NAB);

    // GAT layer 1 (2 dispatches)
    gemm_gat_k<<<dim3((NT + 63) / 64), t256, 0, stream>>>(hcat, wt_gat, bufA, NT,
                                                          prm + P_ASRC, prm + P_ADST,
                                                          es, edv);
    gat_csr_k<<<dim3((NT + 3) / 4), t256, 0, stream>>>(bufA, rp_d, col_d, es, edv,
                                                       prm + P_BGAT, bufB, NT, 1);
    // GAT layer 2 (2 dispatches)
    gemm_gat_k<<<dim3((NT + 63) / 64), t256, 0, stream>>>(bufB, wt_gat2, bufA, NT,
                                                          prm + P_ASRC2, prm + P_ADST2,
                                                          es, edv);
    gat_csr_k<<<dim3((NT + 3) / 4), t256, 0, stream>>>(bufA, rp_d, col_d, es, edv,
                                                       prm + P_BGAT2, bufB, NT, 0);

    // batched final stage (3 dispatches)
    bn_stats_cat2_k<<<dim3(nbg, 2), t512, 0, stream>>>(bufB, hcat, NAB, psum, psq);
    bn_fin_cat2_k<<<dim3(1, 2), t512, 0, stream>>>(psum, psq, stc, NAB, nbg);
    final2_k<<<dim3((NAB + 3) / 4, 2), t256, 0, stream>>>(bufB, hcat, stc, prm,
                                                          (float*)d_out, NAB);
}

// Round 15
// 608.688 us; speedup vs baseline: 1.3200x; 1.0899x over previous
//
#include <hip/hip_runtime.h>
#include <hip/hip_bf16.h>
#include <stdint.h>

#define NF 256
#define EPSV 1e-5f
#define PB 160     // max bn partial blocks
#define MAXBUK 160 // max coarse buckets (dst>>8): 157 for NT=40000

typedef unsigned short u16;
typedef unsigned int u32;
typedef short short8 __attribute__((ext_vector_type(8)));
typedef float floatx4 __attribute__((ext_vector_type(4)));

// param block offsets (floats): 12 x 256, then 6 x 512, then 2 x 1
#define P_BGCN 0
#define P_G1 256
#define P_BE1 512
#define P_BAGG 768
#define P_AGG1 1024
#define P_AGBE1 1280
#define P_ASRC 1536
#define P_ADST 1792
#define P_BGAT 2048
#define P_ASRC2 2304
#define P_ADST2 2560
#define P_BGAT2 2816
#define P_G2 3072
#define P_BE2 3584
#define P_WFC 4096
#define P_AGG2 4608
#define P_AGBE2 5120
#define P_WAGFC 5632
#define P_BFC 6144
#define P_BAGFC 6145

__device__ __forceinline__ float bf2f(u16 u) {
    union { unsigned int i; float f; } v; v.i = ((unsigned int)u) << 16; return v.f;
}
__device__ __forceinline__ u16 f2bf(float f) {
    unsigned int x = __float_as_uint(f);
    unsigned int r = x + 0x7fffu + ((x >> 16) & 1u);
    return (u16)(r >> 16);
}
__device__ __forceinline__ float sane(float f) {
    return (f == f && fabsf(f) < 1e30f) ? f : 0.f;
}
__device__ __forceinline__ unsigned int zap2(unsigned int w) {
    if ((w & 0x00007F80u) == 0x00007F80u) w &= 0xFFFF0000u;
    if ((w & 0x7F800000u) == 0x7F800000u) w &= 0x0000FFFFu;
    return w;
}
__device__ __forceinline__ float lrelu(float x) { return x > 0.f ? x : 0.2f * x; }

__device__ __forceinline__ float4 ld4h(const u16* p) {
    uint2 u = *(const uint2*)p;
    float4 r;
    r.x = bf2f((u16)(u.x & 0xFFFFu)); r.y = bf2f((u16)(u.x >> 16));
    r.z = bf2f((u16)(u.y & 0xFFFFu)); r.w = bf2f((u16)(u.y >> 16));
    return r;
}
__device__ __forceinline__ void st4h(u16* p, float4 v) {
    uint2 u;
    u.x = (unsigned)f2bf(v.x) | ((unsigned)f2bf(v.y) << 16);
    u.y = (unsigned)f2bf(v.z) | ((unsigned)f2bf(v.w) << 16);
    *(uint2*)p = u;
}

__device__ __forceinline__ float wredsum(float v) {
#pragma unroll
    for (int o = 32; o > 0; o >>= 1) v += __shfl_xor(v, o, 64);
    return v;
}
__device__ __forceinline__ int wscan_incl(int x, int lane) {
#pragma unroll
    for (int o = 1; o < 64; o <<= 1) {
        int t = __shfl_up(x, o, 64);
        if (lane >= o) x += t;
    }
    return x;
}

// ---------------- dtype detect ----------------
__global__ void detect_k(const u16* __restrict__ x, int* __restrict__ flag) {
    __shared__ int cnt;
    if (threadIdx.x == 0) cnt = 0;
    __syncthreads();
    int c = 0;
#pragma unroll
    for (int k = 0; k < 4; ++k) {
        unsigned int u = x[2 * (threadIdx.x + 256 * k)];
        int e = (int)((u >> 7) & 0xFFu);
        if (u == 0u || (e >= 100 && e <= 140)) c++;
    }
    atomicAdd(&cnt, c);
    __syncthreads();
    if (threadIdx.x == 0) flag[0] = (cnt >= 512) ? 1 : 0;
}

// ---------------- prep: weight fragment-pack + param cvt + counter zero ----------------
__global__ void prep_k(const void* w0, const void* w1, const void* w2, const void* w3,
                       const void* p0, const void* p1, const void* p2, const void* p3,
                       const void* p4, const void* p5, const void* p6, const void* p7,
                       const void* p8, const void* p9, const void* p10, const void* p11,
                       const void* p12, const void* p13, const void* p14, const void* p15,
                       const void* p16, const void* p17, const void* p18, const void* p19,
                       u16* __restrict__ wtf, float* __restrict__ prm,
                       int* __restrict__ zb, int nz,
                       const int* __restrict__ flagp) {
    int f = flagp[0];
    int idx = blockIdx.x * 256 + threadIdx.x;
    if (idx < nz) zb[idx] = 0;
    if (idx < 262144) {
        const void* ws[4] = {w0, w1, w2, w3};
        int wi = idx >> 16;
        int rest = idx & 65535;
        int j = rest & 7;
        int lr = (rest >> 3) & 15;
        int q = (rest >> 7) & 3;
        int nf = (rest >> 9) & 15;
        int ks = (rest >> 13) & 7;
        int n = nf * 16 + lr;
        int k = ks * 32 + q * 8 + j;
        const void* W = ws[wi];
        u16 v;
        if (f) {
            v = ((const u16*)W)[k * NF + n];
            if ((v & 0x7F80u) == 0x7F80u) v = 0;
        } else {
            v = f2bf(sane(((const float*)W)[k * NF + n]));
        }
        wtf[idx] = v;
        return;
    }
    int pidx = idx - 262144;
    if (pidx >= 6146) return;
    const void* ptrs[20] = {p0, p1, p2, p3, p4, p5, p6, p7, p8, p9,
                            p10, p11, p12, p13, p14, p15, p16, p17, p18, p19};
    int t, j;
    if (pidx < 3072) { t = pidx >> 8; j = pidx & 255; }
    else if (pidx < 6144) { t = 12 + ((pidx - 3072) >> 9); j = (pidx - 3072) & 511; }
    else { t = 18 + (pidx - 6144); j = 0; }
    float v = f ? bf2f(((const u16*)ptrs[t])[j]) : ((const float*)ptrs[t])[j];
    prm[pidx] = sane(v);
}

// ---------------- bucket-level CSR build (y = graph: 0=ab, 1=ag, 2=d) ----------------
// pass 0: coarse bucket counts via LDS histogram (one global atomic per block,bucket)
__global__ __launch_bounds__(256) void bucket_cnt3_k(const int* e0, const int* e1,
                                                     const int* e2,
                                                     int* __restrict__ gbcnt) {
    int y = blockIdx.y;
    const int* ei = (y == 0) ? e0 : (y == 1) ? e1 : e2;
    int E = (y == 2) ? 640000 : 320000;
    int n = (y == 2) ? 40000 : 20000;
    int nbuk = (n + 255) >> 8;
    int base = blockIdx.x * 4096;
    if (base >= E) return;
    __shared__ int l[MAXBUK];
    if (threadIdx.x < nbuk) l[threadIdx.x] = 0;
    __syncthreads();
#pragma unroll
    for (int t = 0; t < 16; ++t) {
        int e = base + t * 256 + threadIdx.x;
        if (e < E) atomicAdd(&l[ei[E + e] >> 8], 1);
    }
    __syncthreads();
    if (threadIdx.x < nbuk) {
        int c = l[threadIdx.x];
        if (c) atomicAdd(&gbcnt[y * MAXBUK + threadIdx.x], c);
    }
}
// pass 1: single block per graph scans bucket counts -> bucket bases bb; rp[n]=E
__global__ __launch_bounds__(256) void bucket_scan3_k(const int* __restrict__ gbcnt,
                                                      int* __restrict__ bb,
                                                      int* rp0, int* rp1, int* rp2) {
    __shared__ int wp[4];
    int y = blockIdx.y;
    int n = (y == 2) ? 40000 : 20000;
    int E = (y == 2) ? 640000 : 320000;
    int nbuk = (n + 255) >> 8;
    int* rp = (y == 0) ? rp0 : (y == 1) ? rp1 : rp2;
    int lane = threadIdx.x & 63, wave = threadIdx.x >> 6;
    int v = (threadIdx.x < nbuk) ? gbcnt[y * MAXBUK + threadIdx.x] : 0;
    int x = wscan_incl(v, lane);
    if (lane == 63) wp[wave] = x;
    __syncthreads();
    int off = 0;
#pragma unroll
    for (int w = 0; w < 4; ++w) off += (w < wave) ? wp[w] : 0;
    if (threadIdx.x < nbuk) bb[y * (MAXBUK + 1) + threadIdx.x] = off + x - v;
    if (threadIdx.x == 0) {
        bb[y * (MAXBUK + 1) + nbuk] = E;
        rp[n] = E;
    }
}
// pass 2: bucket-binned staging. Record = src | (dst&255)<<16.
__global__ __launch_bounds__(256) void bin3_k(const int* e0, const int* e1, const int* e2,
                                              const int* __restrict__ bb,
                                              int* __restrict__ gcur,
                                              u32* s0, u32* s1, u32* s2) {
    int y = blockIdx.y;
    const int* ei = (y == 0) ? e0 : (y == 1) ? e1 : e2;
    u32* stg = (y == 0) ? s0 : (y == 1) ? s1 : s2;
    int E = (y == 2) ? 640000 : 320000;
    int n = (y == 2) ? 40000 : 20000;
    int nbuk = (n + 255) >> 8;
    int base = blockIdx.x * 4096;
    if (base >= E) return;
    __shared__ int lcnt[MAXBUK];
    __shared__ int lbase[MAXBUK];
    if (threadIdx.x < nbuk) lcnt[threadIdx.x] = 0;
    __syncthreads();
#pragma unroll
    for (int t = 0; t < 16; ++t) {
        int e = base + t * 256 + threadIdx.x;
        if (e < E) atomicAdd(&lcnt[ei[E + e] >> 8], 1);
    }
    __syncthreads();
    if (threadIdx.x < nbuk) {
        int cnt = lcnt[threadIdx.x];
        int g = cnt ? atomicAdd(&gcur[y * MAXBUK + threadIdx.x], cnt) : 0;
        lbase[threadIdx.x] = bb[y * (MAXBUK + 1) + threadIdx.x] + g;
        lcnt[threadIdx.x] = 0;
    }
    __syncthreads();
#pragma unroll
    for (int t = 0; t < 16; ++t) {
        int e = base + t * 256 + threadIdx.x;
        if (e < E) {
            int s = ei[e], d = ei[E + e];
            int b = d >> 8;
            int r = atomicAdd(&lcnt[b], 1);
            stg[lbase[b] + r] = (u32)s | ((u32)(d & 255) << 16);
        }
    }
}
// pass 3: one block per bucket: per-dst counts (LDS) -> rp + dinv + ranked col placement
__global__ __launch_bounds__(256) void place3_k(const u32* s0, const u32* s1, const u32* s2,
                                                const int* __restrict__ bb,
                                                int* rp0, int* rp1, int* rp2,
                                                float* dv0, float* dv1,
                                                int* c0, int* c1, int* c2) {
    __shared__ int wp[4];
    __shared__ int lcnt[256];
    __shared__ int lrp[256];
    int y = blockIdx.y;
    int b = blockIdx.x;
    int n = (y == 2) ? 40000 : 20000;
    int nbuk = (n + 255) >> 8;
    if (b >= nbuk) return;
    const u32* stg = (y == 0) ? s0 : (y == 1) ? s1 : s2;
    int* rp = (y == 0) ? rp0 : (y == 1) ? rp1 : rp2;
    int* col = (y == 0) ? c0 : (y == 1) ? c1 : c2;
    int d0 = b << 8;
    int dn = min(256, n - d0);
    int base = bb[y * (MAXBUK + 1) + b];
    int endv = bb[y * (MAXBUK + 1) + b + 1];
    lcnt[threadIdx.x] = 0;
    __syncthreads();
    for (int j = base + threadIdx.x; j < endv; j += 256)
        atomicAdd(&lcnt[stg[j] >> 16], 1);
    __syncthreads();
    // exclusive 256-scan of lcnt -> lrp (+base)
    int lane = threadIdx.x & 63, wave = threadIdx.x >> 6;
    int v = lcnt[threadIdx.x];
    int x = wscan_incl(v, lane);
    if (lane == 63) wp[wave] = x;
    __syncthreads();
    int off = 0;
#pragma unroll
    for (int w = 0; w < 4; ++w) off += (w < wave) ? wp[w] : 0;
    int excl = base + off + x - v;
    lrp[threadIdx.x] = excl;
    if (threadIdx.x < dn) {
        rp[d0 + threadIdx.x] = excl;
        if (y == 0) dv0[d0 + threadIdx.x] = rsqrtf((float)(v + 1));
        else if (y == 1) dv1[d0 + threadIdx.x] = rsqrtf((float)(v + 1));
    }
    lcnt[threadIdx.x] = 0;
    __syncthreads();
    for (int j = base + threadIdx.x; j < endv; j += 256) {
        u32 rec = stg[j];
        int dl = (int)(rec >> 16);
        int s = (int)(rec & 0xFFFFu);
        int r = atomicAdd(&lcnt[dl], 1);
        col[lrp[dl] + r] = s;
    }
}

// ---------------- batched GCN GEMM (y = graph), LDS-free MR=1, frag-ordered B ----------
__global__ __launch_bounds__(256) void gemm2_k(const void* A0, const void* A1,
                                               const u16* __restrict__ Wtf0,
                                               const u16* __restrict__ Wtf1,
                                               const int* __restrict__ flagp,
                                               u16* __restrict__ C, int M) {
    int f = flagp[0];
    int y = blockIdx.y;
    const void* Aptr = y ? A1 : A0;
    const u16* Wtf = y ? Wtf1 : Wtf0;
    u16* Cp = C + (size_t)y * M * NF;
    int wave = threadIdx.x >> 6, lane = threadIdx.x & 63;
    int lr = lane & 15, q = lane >> 4;
    int arow = blockIdx.x * 64 + wave * 16 + lr;
    bool rok = arow < M;
    floatx4 acc[16];
#pragma unroll
    for (int nf = 0; nf < 16; ++nf) acc[nf] = (floatx4){0.f, 0.f, 0.f, 0.f};
    const u16* a16 = (const u16*)Aptr + (size_t)arow * NF;
    const float* a32 = (const float*)Aptr + (size_t)arow * NF;
#pragma unroll
    for (int ks = 0; ks < 8; ++ks) {
        int kk = ks * 32 + q * 8;
        union { u16 s[8]; uint4 u; short8 v; } a;
        if (!rok) {
            a.u = make_uint4(0u, 0u, 0u, 0u);
        } else if (f) {
            a.u = *(const uint4*)(a16 + kk);
            a.u.x = zap2(a.u.x); a.u.y = zap2(a.u.y);
            a.u.z = zap2(a.u.z); a.u.w = zap2(a.u.w);
        } else {
            float4 f0 = *(const float4*)(a32 + kk);
            float4 f1 = *(const float4*)(a32 + kk + 4);
            a.s[0] = f2bf(sane(f0.x)); a.s[1] = f2bf(sane(f0.y));
            a.s[2] = f2bf(sane(f0.z)); a.s[3] = f2bf(sane(f0.w));
            a.s[4] = f2bf(sane(f1.x)); a.s[5] = f2bf(sane(f1.y));
            a.s[6] = f2bf(sane(f1.z)); a.s[7] = f2bf(sane(f1.w));
        }
        const u16* bbase = Wtf + ks * 8192 + lane * 8;
#pragma unroll
        for (int nf = 0; nf < 16; ++nf) {
            short8 b = *(const short8*)(bbase + nf * 512);
            acc[nf] = __builtin_amdgcn_mfma_f32_16x16x32_bf16(a.v, b, acc[nf], 0, 0, 0);
        }
    }
#pragma unroll
    for (int nf = 0; nf < 16; ++nf) {
#pragma unroll
        for (int rr = 0; rr < 4; ++rr) {
            int gr = blockIdx.x * 64 + wave * 16 + q * 4 + rr;
            if (gr < M) Cp[(size_t)gr * NF + nf * 16 + lr] = f2bf(acc[nf][rr]);
        }
    }
}

// ---------------- GAT GEMM MR=1, fused scores epilogue (bf16 ws input) ----------------
__global__ __launch_bounds__(256) void gemm_gat_k(const u16* __restrict__ Aptr,
                                                  const u16* __restrict__ Wtf,
                                                  u16* __restrict__ C, int M,
                                                  const float* __restrict__ as_,
                                                  const float* __restrict__ ad_,
                                                  float* __restrict__ es,
                                                  float* __restrict__ ed) {
    int wave = threadIdx.x >> 6, lane = threadIdx.x & 63;
    int lr = lane & 15, q = lane >> 4;
    int arow = blockIdx.x * 64 + wave * 16 + lr;
    bool rok = arow < M;
    floatx4 acc[16];
#pragma unroll
    for (int nf = 0; nf < 16; ++nf) acc[nf] = (floatx4){0.f, 0.f, 0.f, 0.f};
    const u16* a16 = Aptr + (size_t)arow * NF;
#pragma unroll
    for (int ks = 0; ks < 8; ++ks) {
        int kk = ks * 32 + q * 8;
        union { uint4 u; short8 v; } a;
        a.u = rok ? *(const uint4*)(a16 + kk) : make_uint4(0u, 0u, 0u, 0u);
        const u16* bbase = Wtf + ks * 8192 + lane * 8;
#pragma unroll
        for (int nf = 0; nf < 16; ++nf) {
            short8 b = *(const short8*)(bbase + nf * 512);
            acc[nf] = __builtin_amdgcn_mfma_f32_16x16x32_bf16(a.v, b, acc[nf], 0, 0, 0);
        }
    }
#pragma unroll
    for (int nf = 0; nf < 16; ++nf) {
#pragma unroll
        for (int rr = 0; rr < 4; ++rr) {
            int gr = blockIdx.x * 64 + wave * 16 + q * 4 + rr;
            if (gr < M) C[(size_t)gr * NF + nf * 16 + lr] = f2bf(acc[nf][rr]);
        }
    }
    float asl[16], adl[16];
#pragma unroll
    for (int nf = 0; nf < 16; ++nf) { asl[nf] = as_[nf * 16 + lr]; adl[nf] = ad_[nf * 16 + lr]; }
#pragma unroll
    for (int rr = 0; rr < 4; ++rr) {
        float s1 = 0.f, s2 = 0.f;
#pragma unroll
        for (int nf = 0; nf < 16; ++nf) {
            s1 += acc[nf][rr] * asl[nf];
            s2 += acc[nf][rr] * adl[nf];
        }
#pragma unroll
        for (int o = 1; o < 16; o <<= 1) {
            s1 += __shfl_xor(s1, o, 64);
            s2 += __shfl_xor(s2, o, 64);
        }
        int gr = blockIdx.x * 64 + wave * 16 + q * 4 + rr;
        if (lr == 0 && gr < M) { es[gr] = s1; ed[gr] = s2; }
    }
}

// ---------------- batched GCN aggregation via CSR (y = graph) ----------------
__global__ __launch_bounds__(256) void gcn_csr2_k(const u16* __restrict__ h,
                                                  const int* rp0, const int* rp1,
                                                  const int* c0, const int* c1,
                                                  const float* dv0, const float* dv1,
                                                  const float* __restrict__ prm,
                                                  u16* __restrict__ out, int n) {
    int y = blockIdx.y;
    const int* rp = y ? rp1 : rp0;
    const int* col = y ? c1 : c0;
    const float* dinv = y ? dv1 : dv0;
    const float* b = prm + (y ? P_BAGG : P_BGCN);
    const u16* hb = h + (size_t)y * n * NF;
    u16* ob = out + (size_t)y * n * NF;
    int wave = threadIdx.x >> 6, lane = threadIdx.x & 63;
    int i = blockIdx.x * 4 + wave;
    if (i >= n) return;
    int c = lane * 4;
    int beg = rp[i], end = rp[i + 1];
    float di = dinv[i];
    float4 hv = ld4h(hb + (size_t)i * NF + c);
    float w = di * di;
    float4 acc;
    acc.x = hv.x * w + b[c + 0];
    acc.y = hv.y * w + b[c + 1];
    acc.z = hv.z * w + b[c + 2];
    acc.w = hv.w * w + b[c + 3];
    int j = beg;
    for (; j + 3 < end; j += 4) {
        int s0 = col[j], s1 = col[j + 1], s2 = col[j + 2], s3 = col[j + 3];
        float n0 = dinv[s0] * di, n1 = dinv[s1] * di, n2 = dinv[s2] * di, n3 = dinv[s3] * di;
        float4 h0 = ld4h(hb + (size_t)s0 * NF + c);
        float4 h1 = ld4h(hb + (size_t)s1 * NF + c);
        float4 h2 = ld4h(hb + (size_t)s2 * NF + c);
        float4 h3 = ld4h(hb + (size_t)s3 * NF + c);
        acc.x += h0.x * n0 + h1.x * n1 + h2.x * n2 + h3.x * n3;
        acc.y += h0.y * n0 + h1.y * n1 + h2.y * n2 + h3.y * n3;
        acc.z += h0.z * n0 + h1.z * n1 + h2.z * n2 + h3.z * n3;
        acc.w += h0.w * n0 + h1.w * n1 + h2.w * n2 + h3.w * n3;
    }
    for (; j < end; ++j) {
        int s = col[j];
        float nrm = dinv[s] * di;
        float4 hs = ld4h(hb + (size_t)s * NF + c);
        acc.x += hs.x * nrm;
        acc.y += hs.y * nrm;
        acc.z += hs.z * nrm;
        acc.w += hs.w * nrm;
    }
    st4h(ob + (size_t)i * NF + c, acc);
}

// ---------------- BN partial stats (no atomics) ----------------
__global__ void bn_stats2_k(const u16* __restrict__ x, int n,
                            float* __restrict__ psum, float* __restrict__ psq) {
    int y = blockIdx.y;
    int c = threadIdx.x;  // 256
    int r0 = blockIdx.x * 128;
    int rend = min(r0 + 128, n);
    const u16* xb = x + (size_t)y * n * NF;
    float s = 0.f, qq = 0.f;
    for (int r = r0; r < rend; ++r) {
        float v = bf2f(xb[(size_t)r * NF + c]);
        s += v; qq += v * v;
    }
    size_t o = (size_t)(y * PB + blockIdx.x) * 512 + c;
    psum[o] = s; psq[o] = qq;
}
__global__ void bn_fin2_k(const float* __restrict__ psum, const float* __restrict__ psq,
                          float* __restrict__ stg, int n, int nb) {
    int y = blockIdx.y;
    int c = threadIdx.x;  // 256
    float s = 0.f, qq = 0.f;
    for (int b = 0; b < nb; ++b) {
        size_t o = (size_t)(y * PB + b) * 512 + c;
        s += psum[o]; qq += psq[o];
    }
    float inv_n = 1.0f / (float)n;
    float mean = s * inv_n;
    float var = fmaxf(qq * inv_n - mean * mean, 0.f);
    stg[y * 512 + c] = mean;
    stg[y * 512 + 256 + c] = rsqrtf(var + EPSV);
}
__global__ void bn_apply2_k(const u16* __restrict__ x, const float* __restrict__ stg,
                            const float* __restrict__ prm, u16* __restrict__ out, int n) {
    int y = blockIdx.y;
    int t = blockIdx.x * 256 + threadIdx.x;
    if (t >= n * NF) return;
    int c = t & 255;
    const float* st = stg + y * 512;
    const float* g = prm + (y ? P_AGG1 : P_G1);
    const float* be = prm + (y ? P_AGBE1 : P_BE1);
    float v = (bf2f(x[(size_t)y * n * NF + t]) - st[c]) * st[256 + c] * g[c] + be[c];
    out[(size_t)y * n * NF + t] = f2bf(fmaxf(v, 0.f));
}

// ---------------- single-pass fused GAT aggregation via CSR ----------------
__global__ __launch_bounds__(256) void gat_csr_k(const u16* __restrict__ h,
                                                 const int* __restrict__ rp,
                                                 const int* __restrict__ col,
                                                 const float* __restrict__ es,
                                                 const float* __restrict__ ed,
                                                 const float* __restrict__ b,
                                                 u16* __restrict__ out, int n,
                                                 int do_relu) {
    int wave = threadIdx.x >> 6, lane = threadIdx.x & 63;
    int i = blockIdx.x * 4 + wave;
    if (i >= n) return;
    int beg = rp[i], end = rp[i + 1];
    float edi = ed[i];
    float ws = __expf(lrelu(es[i] + edi));
    int c = lane * 4;
    float4 hv = ld4h(h + (size_t)i * NF + c);
    float ssum = ws;
    float4 acc;
    acc.x = ws * hv.x; acc.y = ws * hv.y; acc.z = ws * hv.z; acc.w = ws * hv.w;
    int j = beg;
    for (; j + 3 < end; j += 4) {
        int s0 = col[j], s1 = col[j + 1], s2 = col[j + 2], s3 = col[j + 3];
        float4 h0 = ld4h(h + (size_t)s0 * NF + c);
        float4 h1 = ld4h(h + (size_t)s1 * NF + c);
        float4 h2 = ld4h(h + (size_t)s2 * NF + c);
        float4 h3 = ld4h(h + (size_t)s3 * NF + c);
        float a0 = __expf(lrelu(es[s0] + edi));
        float a1 = __expf(lrelu(es[s1] + edi));
        float a2 = __expf(lrelu(es[s2] + edi));
        float a3 = __expf(lrelu(es[s3] + edi));
        ssum += a0 + a1 + a2 + a3;
        acc.x += h0.x * a0 + h1.x * a1 + h2.x * a2 + h3.x * a3;
        acc.y += h0.y * a0 + h1.y * a1 + h2.y * a2 + h3.y * a3;
        acc.z += h0.z * a0 + h1.z * a1 + h2.z * a2 + h3.z * a3;
        acc.w += h0.w * a0 + h1.w * a1 + h2.w * a2 + h3.w * a3;
    }
    for (; j < end; ++j) {
        int s = col[j];
        float a = __expf(lrelu(es[s] + edi));
        float4 hs = ld4h(h + (size_t)s * NF + c);
        ssum += a;
        acc.x += a * hs.x;
        acc.y += a * hs.y;
        acc.z += a * hs.z;
        acc.w += a * hs.w;
    }
    float inv = 1.0f / ssum;
    acc.x = b[c + 0] + acc.x * inv;
    acc.y = b[c + 1] + acc.y * inv;
    acc.z = b[c + 2] + acc.z * inv;
    acc.w = b[c + 3] + acc.w * inv;
    if (do_relu) {
        acc.x = fmaxf(acc.x, 0.f); acc.y = fmaxf(acc.y, 0.f);
        acc.z = fmaxf(acc.z, 0.f); acc.w = fmaxf(acc.w, 0.f);
    }
    st4h(out + (size_t)i * NF + c, acc);
}

// ---------------- batched final-stage BN stats over cat(x,h) (512 ch) ----------------
__global__ void bn_stats_cat2_k(const u16* __restrict__ xp, const u16* __restrict__ hp,
                                int n, float* __restrict__ psum, float* __restrict__ psq) {
    int y = blockIdx.y;
    int c = threadIdx.x;  // 512
    int r0 = blockIdx.x * 128;
    int rend = min(r0 + 128, n);
    const u16* src = ((c < 256) ? xp : hp) + (size_t)y * n * NF;
    int cc = c & 255;
    float s = 0.f, qq = 0.f;
    for (int r = r0; r < rend; ++r) {
        float v = bf2f(src[(size_t)r * NF + cc]);
        s += v; qq += v * v;
    }
    size_t o = (size_t)(y * PB + blockIdx.x) * 512 + c;
    psum[o] = s; psq[o] = qq;
}
__global__ void bn_fin_cat2_k(const float* __restrict__ psum, const float* __restrict__ psq,
                              float* __restrict__ stc, int n, int nb) {
    int y = blockIdx.y;
    int c = threadIdx.x;  // 512
    float s = 0.f, qq = 0.f;
    for (int b = 0; b < nb; ++b) {
        size_t o = (size_t)(y * PB + b) * 512 + c;
        s += psum[o]; qq += psq[o];
    }
    float inv_n = 1.0f / (float)n;
    float mean = s * inv_n;
    float var = fmaxf(qq * inv_n - mean * mean, 0.f);
    stc[y * 1024 + c] = mean;
    stc[y * 1024 + 512 + c] = rsqrtf(var + EPSV);
}
__global__ void final2_k(const u16* __restrict__ xp, const u16* __restrict__ hp,
                         const float* __restrict__ stc, const float* __restrict__ prm,
                         float* __restrict__ out, int n) {
    int y = blockIdx.y;
    int wave = threadIdx.x >> 6, lane = threadIdx.x & 63;
    int i = blockIdx.x * 4 + wave;
    if (i >= n) return;
    const float* st = stc + y * 1024;
    const float* g = prm + (y ? P_AGG2 : P_G2);
    const float* be = prm + (y ? P_AGBE2 : P_BE2);
    const float* w = prm + (y ? P_WAGFC : P_WFC);
    float bias = prm[y ? P_BAGFC : P_BFC];
    const u16* src = (((lane < 32) ? xp : hp) + (size_t)y * n * NF) + (size_t)i * NF
                     + (lane < 32 ? lane * 8 : (lane - 32) * 8);
    uint4 u = *(const uint4*)src;
    float vv[8];
    vv[0] = bf2f((u16)(u.x & 0xFFFFu)); vv[1] = bf2f((u16)(u.x >> 16));
    vv[2] = bf2f((u16)(u.y & 0xFFFFu)); vv[3] = bf2f((u16)(u.y >> 16));
    vv[4] = bf2f((u16)(u.z & 0xFFFFu)); vv[5] = bf2f((u16)(u.z >> 16));
    vv[6] = bf2f((u16)(u.w & 0xFFFFu)); vv[7] = bf2f((u16)(u.w >> 16));
    int c0 = lane * 8;
    float acc = 0.f;
#pragma unroll
    for (int j = 0; j < 8; ++j) {
        int c = c0 + j;
        float v = (vv[j] - st[c]) * st[512 + c] * g[c] + be[c];
        v = fmaxf(v, 0.f);
        acc += v * w[c];
    }
    acc = wredsum(acc);
    if (lane == 0) out[(size_t)y * 20000 + i] = acc + bias;
}

// ---------------- host ----------------
extern "C" void kernel_launch(void* const* d_in, const int* in_sizes, int n_in,
                              void* d_out, int out_size, void* d_ws, size_t ws_size,
                              hipStream_t stream) {
    const void* x_ab = d_in[0];
    const void* x_ag = d_in[1];
    const int* e_ab = (const int*)d_in[26];
    const int* e_ag = (const int*)d_in[27];
    const int* e_d = (const int*)d_in[28];

    const int NAB = 20000, NT = 40000;
    const int EAB = 320000, EAG = 320000, ED = 640000;

    u16* hcat = (u16*)d_ws;                     // NT*NF u16
    u16* bufA = hcat + (size_t)NT * NF;         // NT*NF u16
    u16* bufB = bufA + (size_t)NT * NF;         // NT*NF u16
    u16* wt4 = bufB + (size_t)NT * NF;          // 4*65536 u16
    float* dv0 = (float*)(wt4 + 4 * 65536);     // NAB
    float* dv1 = dv0 + NAB;                     // NAB
    float* es = dv1 + NAB;                      // NT
    float* edv = es + NT;                       // NT
    float* stg2 = edv + NT;                     // 1024
    float* stc = stg2 + 1024;                   // 2048
    float* psum = stc + 2048;                   // 2*PB*512
    float* psq = psum + 2 * PB * 512;           // 2*PB*512
    float* prm = psq + 2 * PB * 512;            // 8192
    int* flag = (int*)(prm + 8192);             // 16
    int* rp_ab = flag + 16;                     // NAB+1
    int* rp_ag = rp_ab + NAB + 1;               // NAB+1
    int* rp_d = rp_ag + NAB + 1;                // NT+1
    int* gbcnt = rp_d + NT + 1;                 // 3*MAXBUK
    int* gcur = gbcnt + 3 * MAXBUK;             // 3*MAXBUK
    int* bb = gcur + 3 * MAXBUK;                // 3*(MAXBUK+1)
    int* col_ab = bb + 3 * (MAXBUK + 1);        // EAB
    int* col_ag = col_ab + EAB;                 // EAG
    int* col_d = col_ag + EAG;                  // ED
    u32* stg_ab = (u32*)(col_d + ED);           // EAB
    u32* stg_ag = stg_ab + EAB;                 // EAG
    u32* stg_d = stg_ag + EAG;                  // ED

    u16* wt_gcn = wt4;
    u16* wt_aggcn = wt4 + 65536;
    u16* wt_gat = wt4 + 2 * 65536;
    u16* wt_gat2 = wt4 + 3 * 65536;

    dim3 t256(256), t512(512);
    const int nbg = (NAB + 127) / 128;   // 157 bn partial blocks per graph

    detect_k<<<dim3(1), t256, 0, stream>>>((const u16*)x_ab, flag);
    prep_k<<<dim3(1049), t256, 0, stream>>>(
        d_in[2], d_in[6], d_in[10], d_in[14],
        d_in[3], d_in[4], d_in[5], d_in[7], d_in[8], d_in[9],
        d_in[11], d_in[12], d_in[13], d_in[15], d_in[16], d_in[17],
        d_in[22], d_in[23], d_in[24], d_in[18], d_in[19], d_in[20],
        d_in[25], d_in[21], wt4, prm, gbcnt, 6 * MAXBUK + 3 * (MAXBUK + 1), flag);

    // bucket-level CSR build (4 dispatches)
    bucket_cnt3_k<<<dim3(157, 3), t256, 0, stream>>>(e_ab, e_ag, e_d, gbcnt);
    bucket_scan3_k<<<dim3(1, 3), t256, 0, stream>>>(gbcnt, bb, rp_ab, rp_ag, rp_d);
    bin3_k<<<dim3(157, 3), t256, 0, stream>>>(e_ab, e_ag, e_d, bb, gcur,
                                              stg_ab, stg_ag, stg_d);
    place3_k<<<dim3(157, 3), t256, 0, stream>>>(stg_ab, stg_ag, stg_d, bb,
                                                rp_ab, rp_ag, rp_d, dv0, dv1,
                                                col_ab, col_ag, col_d);

    // batched GCN stage (5 dispatches)
    gemm2_k<<<dim3((NAB + 63) / 64, 2), t256, 0, stream>>>(x_ab, x_ag, wt_gcn, wt_aggcn,
                                                           flag, bufA, NAB);
    gcn_csr2_k<<<dim3((NAB + 3) / 4, 2), t256, 0, stream>>>(bufA, rp_ab, rp_ag,
                                                            col_ab, col_ag, dv0, dv1,
                                                            prm, bufB, NAB);
    bn_stats2_k<<<dim3(nbg, 2), t256, 0, stream>>>(bufB, NAB, psum, psq);
    bn_fin2_k<<<dim3(1, 2), t256, 0, stream>>>(psum, psq, stg2, NAB, nbg);
    bn_apply2_k<<<dim3((NAB * NF + 255) / 256, 2), t256, 0, stream>>>(bufB, stg2, prm,
                                                                      hcat, NAB);

    // GAT layer 1 (2 dispatches)
    gemm_gat_k<<<dim3((NT + 63) / 64), t256, 0, stream>>>(hcat, wt_gat, bufA, NT,
                                                          prm + P_ASRC, prm + P_ADST,
                                                          es, edv);
    gat_csr_k<<<dim3((NT + 3) / 4), t256, 0, stream>>>(bufA, rp_d, col_d, es, edv,
                                                       prm + P_BGAT, bufB, NT, 1);
    // GAT layer 2 (2 dispatches)
    gemm_gat_k<<<dim3((NT + 63) / 64), t256, 0, stream>>>(bufB, wt_gat2, bufA, NT,
                                                          prm + P_ASRC2, prm + P_ADST2,
                                                          es, edv);
    gat_csr_k<<<dim3((NT + 3) / 4), t256, 0, stream>>>(bufA, rp_d, col_d, es, edv,
                                                       prm + P_BGAT2, bufB, NT, 0);

    // batched final stage (3 dispatches)
    bn_stats_cat2_k<<<dim3(nbg, 2), t512, 0, stream>>>(bufB, hcat, NAB, psum, psq);
    bn_fin_cat2_k<<<dim3(1, 2), t512, 0, stream>>>(psum, psq, stc, NAB, nbg);
    final2_k<<<dim3((NAB + 3) / 4, 2), t256, 0, stream>>>(bufB, hcat, stc, prm,
                                                          (float*)d_out, NAB);
}